// Round 13
// baseline (118.225 us; speedup 1.0000x reference)
//
#include <hip/hip_runtime.h>

#define S_ 1024
#define E_ 768
#define H_ 12
#define R_ 32
#define D_ 64
#define RS_ 1056  // R_+S_

// exp2-domain constants: L = log2(e), LN2 = 1/L
#define L2E 1.4426950408889634f
#define LN2F 0.6931471805599453f

#if __has_builtin(__builtin_amdgcn_exp2f)
#define EXP2(x) __builtin_amdgcn_exp2f(x)
#else
#define EXP2(x) exp2f(x)
#endif

typedef _Float16 f16x8 __attribute__((ext_vector_type(8)));
typedef __fp16   fp16x2 __attribute__((ext_vector_type(2)));  // cvt_pkrtz return type
typedef __bf16   bf16x8 __attribute__((ext_vector_type(8)));
typedef float    f32x4 __attribute__((ext_vector_type(4)));

__device__ __forceinline__ f32x4 mf16(f16x8 a, f16x8 b, f32x4 c) {
  return __builtin_amdgcn_mfma_f32_16x16x32_f16(a, b, c, 0, 0, 0);
}
__device__ __forceinline__ f32x4 mbf(bf16x8 a, bf16x8 b, f32x4 c) {
  return __builtin_amdgcn_mfma_f32_16x16x32_bf16(a, b, c, 0, 0, 0);
}
__device__ __forceinline__ f16x8 cvt8(float4 a, float4 b) {
  f16x8 r;
  r[0] = (_Float16)a.x; r[1] = (_Float16)a.y; r[2] = (_Float16)a.z; r[3] = (_Float16)a.w;
  r[4] = (_Float16)b.x; r[5] = (_Float16)b.y; r[6] = (_Float16)b.z; r[7] = (_Float16)b.w;
  return r;
}

// ---------------------------------------------------------------------------
// Prep: fold fuzzy quadratic form into GEMM operands, exp2 domain.
// ---------------------------------------------------------------------------
__global__ __launch_bounds__(64) void prep_rules(const float* __restrict__ RK,
                                                 const float* __restrict__ RW,
                                                 __bf16* __restrict__ W1b,
                                                 __bf16* __restrict__ W2b,
                                                 float* __restrict__ cb) {
  int hr = blockIdx.x;  // 0..383 = h*32 + r
  int d = threadIdx.x;
  long idx = (long)hr * 64 + d;
  float w = RW[idx];
  float wi = 1.0f / w;
  float w2 = wi * wi;
  float rk = RK[idx];
  W1b[idx] = (__bf16)(-w2 * (LN2F / 524288.0f));
  W2b[idx] = (__bf16)(rk * w2 * (1.0f / 4096.0f));
  float part = rk * rk * w2;
  part += __shfl_xor(part, 1);
  part += __shfl_xor(part, 2);
  part += __shfl_xor(part, 4);
  part += __shfl_xor(part, 8);
  part += __shfl_xor(part, 16);
  part += __shfl_xor(part, 32);
  if (d == 0) cb[hr] = -part * (L2E / 128.0f);
}

// ---------------------------------------------------------------------------
// Kernel 1: per-head Q/K projections via MFMA, zero LDS. Q scaled 8*log2(e).
// ---------------------------------------------------------------------------
__global__ __launch_bounds__(256) void qk_proj_mfma(const float* __restrict__ query,
                                                    const float* __restrict__ key,
                                                    const float* __restrict__ Wq,
                                                    const float* __restrict__ Wk,
                                                    _Float16* __restrict__ Qh,
                                                    _Float16* __restrict__ Kh) {
  int blk = blockIdx.x;
  int st = blk & 15;
  int h  = (blk >> 4) % H_;
  int b  = blk / (16 * H_);
  int tid = threadIdx.x;
  int w = tid >> 6, l = tid & 63, lo = l & 15, g = l >> 4;

  int s_in = st * 64 + w * 16 + lo;
  const float* qp = query + ((long)(b * S_) + s_in) * E_ + h * 64;
  const float* kp = key   + ((long)(b * S_) + s_in) * E_ + h * 64;
  float4 a0 = *(const float4*)(qp + g * 8);
  float4 a1 = *(const float4*)(qp + g * 8 + 4);
  float4 a2 = *(const float4*)(qp + 32 + g * 8);
  float4 a3 = *(const float4*)(qp + 32 + g * 8 + 4);
  f16x8 xq0 = cvt8(a0, a1), xq1 = cvt8(a2, a3);
  a0 = *(const float4*)(kp + g * 8);
  a1 = *(const float4*)(kp + g * 8 + 4);
  a2 = *(const float4*)(kp + 32 + g * 8);
  a3 = *(const float4*)(kp + 32 + g * 8 + 4);
  f16x8 xk0 = cvt8(a0, a1), xk1 = cvt8(a2, a3);

  f32x4 accq[4], acck[4];
#pragma unroll
  for (int ns = 0; ns < 4; ++ns)
#pragma unroll
    for (int q = 0; q < 4; ++q) { accq[ns][q] = 0.f; acck[ns][q] = 0.f; }

#pragma unroll
  for (int ns = 0; ns < 4; ++ns) {
    const float* wqp = Wq + (long)(ns * 16 + lo) * 64;
    const float* wkp = Wk + (long)(ns * 16 + lo) * 64;
    float4 b0 = *(const float4*)(wqp + g * 8);
    float4 b1 = *(const float4*)(wqp + g * 8 + 4);
    float4 b2 = *(const float4*)(wqp + 32 + g * 8);
    float4 b3 = *(const float4*)(wqp + 32 + g * 8 + 4);
    f16x8 bq0 = cvt8(b0, b1), bq1 = cvt8(b2, b3);
    b0 = *(const float4*)(wkp + g * 8);
    b1 = *(const float4*)(wkp + g * 8 + 4);
    b2 = *(const float4*)(wkp + 32 + g * 8);
    b3 = *(const float4*)(wkp + 32 + g * 8 + 4);
    f16x8 bk0 = cvt8(b0, b1), bk1 = cvt8(b2, b3);
    accq[ns] = mf16(xq0, bq0, accq[ns]);
    accq[ns] = mf16(xq1, bq1, accq[ns]);
    acck[ns] = mf16(xk0, bk0, acck[ns]);
    acck[ns] = mf16(xk1, bk1, acck[ns]);
  }

  long rowbase = (long)(b * H_ + h) * S_ + st * 64 + w * 16;
#pragma unroll
  for (int ns = 0; ns < 4; ++ns) {
#pragma unroll
    for (int reg = 0; reg < 4; ++reg) {
      long off = (rowbase + g * 4 + reg) * 64 + ns * 16 + lo;
      Qh[off] = (_Float16)(accq[ns][reg] * (8.0f * L2E));
      Kh[off] = (_Float16)acck[ns][reg];
    }
  }
}

// ---------------------------------------------------------------------------
// Kernel 2: MFMA value projection, value staged directly (fused transpose).
// ---------------------------------------------------------------------------
__global__ __launch_bounds__(256) void v_proj_mfma(const float* __restrict__ Wv,
                                                   const float* __restrict__ bv,
                                                   const float* __restrict__ value,
                                                   _Float16* __restrict__ VPT) {
  __shared__ alignas(16) _Float16 As[2][64][72];
  __shared__ alignas(16) _Float16 Bs[2][64][72];

  int tid = threadIdx.x;
  int blk = blockIdx.x;
  int et = blk % 12;
  int rt = (blk / 12) % 17;
  int b  = blk / (12 * 17);
  int r0 = rt * 64, e0 = et * 64;
  int w = tid >> 6, l = tid & 63, lo = l & 15, g = l >> 4;
  int i = tid >> 2, part = tid & 3;

  bool rvalid = (r0 + i) < RS_;
  const float* wvp = Wv + (long)(r0 + i) * S_ + part * 16;
  const float* vbase = value + (long)(b * S_) * E_ + e0 + part * 16;

  f32x4 acc[4];
#pragma unroll
  for (int ns = 0; ns < 4; ++ns)
#pragma unroll
    for (int q = 0; q < 4; ++q) acc[ns][q] = 0.f;

  auto STAGE = [&](int kb, int bufi) {
    float4 x0, x1, x2, x3;
    if (rvalid) {
      const float4* p = (const float4*)(wvp + kb);
      x0 = p[0]; x1 = p[1]; x2 = p[2]; x3 = p[3];
    } else {
      x0 = x1 = x2 = x3 = make_float4(0.f, 0.f, 0.f, 0.f);
    }
    *(f16x8*)&As[bufi][i][part * 16]     = cvt8(x0, x1);
    *(f16x8*)&As[bufi][i][part * 16 + 8] = cvt8(x2, x3);
    const float4* vp = (const float4*)(vbase + (long)(kb + i) * E_);
    float4 y0 = vp[0], y1 = vp[1], y2 = vp[2], y3 = vp[3];
    Bs[bufi][part * 16 +  0][i] = (_Float16)y0.x;
    Bs[bufi][part * 16 +  1][i] = (_Float16)y0.y;
    Bs[bufi][part * 16 +  2][i] = (_Float16)y0.z;
    Bs[bufi][part * 16 +  3][i] = (_Float16)y0.w;
    Bs[bufi][part * 16 +  4][i] = (_Float16)y1.x;
    Bs[bufi][part * 16 +  5][i] = (_Float16)y1.y;
    Bs[bufi][part * 16 +  6][i] = (_Float16)y1.z;
    Bs[bufi][part * 16 +  7][i] = (_Float16)y1.w;
    Bs[bufi][part * 16 +  8][i] = (_Float16)y2.x;
    Bs[bufi][part * 16 +  9][i] = (_Float16)y2.y;
    Bs[bufi][part * 16 + 10][i] = (_Float16)y2.z;
    Bs[bufi][part * 16 + 11][i] = (_Float16)y2.w;
    Bs[bufi][part * 16 + 12][i] = (_Float16)y3.x;
    Bs[bufi][part * 16 + 13][i] = (_Float16)y3.y;
    Bs[bufi][part * 16 + 14][i] = (_Float16)y3.z;
    Bs[bufi][part * 16 + 15][i] = (_Float16)y3.w;
  };

  STAGE(0, 0);
  __syncthreads();
  for (int k = 0; k < 16; ++k) {
    if (k < 15) STAGE((k + 1) * 64, (k + 1) & 1);
    int bi = k & 1;
#pragma unroll
    for (int kc = 0; kc < 2; ++kc) {
      f16x8 af = *(const f16x8*)&As[bi][w * 16 + lo][kc * 32 + g * 8];
#pragma unroll
      for (int ns = 0; ns < 4; ++ns) {
        f16x8 bf = *(const f16x8*)&Bs[bi][ns * 16 + lo][kc * 32 + g * 8];
        acc[ns] = mf16(af, bf, acc[ns]);
      }
    }
    __syncthreads();
  }

  float bvr[4];
#pragma unroll
  for (int reg = 0; reg < 4; ++reg) {
    int r = r0 + w * 16 + g * 4 + reg;
    bvr[reg] = (r < RS_) ? bv[r] : 0.f;
  }
  float* Ct = (float*)&As[0][0][0];  // Ct[d][rloc], stride 69
#pragma unroll
  for (int ns = 0; ns < 4; ++ns)
#pragma unroll
    for (int reg = 0; reg < 4; ++reg)
      Ct[(ns * 16 + lo) * 69 + w * 16 + g * 4 + reg] = acc[ns][reg] + bvr[reg];
  __syncthreads();

  if (r0 + part * 16 < RS_) {
    f16x8 o0, o1;
#pragma unroll
    for (int q = 0; q < 8; ++q) o0[q] = (_Float16)Ct[i * 69 + part * 16 + q];
#pragma unroll
    for (int q = 0; q < 8; ++q) o1[q] = (_Float16)Ct[i * 69 + part * 16 + 8 + q];
    _Float16* op = VPT + ((long)((b * H_ + et) * 64 + i)) * RS_ + r0 + part * 16;
    *(f16x8*)op = o0;
    *((f16x8*)op + 1) = o1;
  }
}

// ---------------------------------------------------------------------------
// Kernel 3: MFMA flash attention, 32-row q-tile, LDS-staged K/V double-buffer.
// qsub0 wave stages K (coalesced), qsub1 stages V; tiles shared per half.
// K tile swizzle: pos(r,cs)=r*128+((cs^(r&7))<<4); V: rv*64+((cv^((rv>>1)&3))<<4).
// grid = B*H*32 = 768 (3 blocks/CU, 40KB LDS).
// ---------------------------------------------------------------------------
__global__ __launch_bounds__(256) void attn_mfma(
    const _Float16* __restrict__ Qh, const _Float16* __restrict__ Kh,
    const _Float16* __restrict__ VPT, const __bf16* __restrict__ W1b,
    const __bf16* __restrict__ W2b, const float* __restrict__ cb,
    _Float16* __restrict__ AO) {
  __shared__ alignas(16) char pool[40960];
  // loop layout:   KT [buf2][half2] 4KB @0       VT [buf2][half2] 4KB @16384
  //                Plds [4][16][40] f16 @32768   fwlds [2][16][40] f16 @37888
  // epilogue alias: OBl [2][64][17] f32 @0, Olds [2][16][68] f32 @8704,
  //                 mrgM @17408, mrgL @17536   (KT/VT dead after last barrier)

  int tid = threadIdx.x;
  int wv = tid >> 6;
  int qsub = wv >> 1;           // 0/1: q-subtile
  int half = wv & 1;            // 0/1: key half
  int l = tid & 63;
  int lo = l & 15, g = l >> 4;

  int bh = blockIdx.x >> 5;
  int qt = blockIdx.x & 31;
  int b = bh / H_, h = bh % H_;
  int s0 = qt * 32;

  const _Float16* Qw = Qh + ((long)bh * S_ + s0 + qsub * 16) * 64;
  const _Float16* Kw = Kh + (long)bh * S_ * 64;
  const _Float16* Vw = VPT + (long)bh * 64 * RS_;

  _Float16* Plw = (_Float16*)(pool + 32768) + wv * 640 + lo * 40;  // lane's P row
  _Float16* fww = (_Float16*)(pool + 37888) + qsub * 640;          // [16][40]

  f16x8 qa0 = *(const f16x8*)(Qw + (long)lo * 64 + g * 8);
  f16x8 qa1 = *(const f16x8*)(Qw + (long)lo * 64 + 32 + g * 8);

  int kb0 = half * 512;

  uint4 sr[4];
  auto LOAD = [&](int kb) {
    if (qsub == 0) {
#pragma unroll
      for (int t = 0; t < 4; ++t)
        sr[t] = *(const uint4*)(Kw + (long)(kb + t * 8 + (l >> 3)) * 64 + (l & 7) * 8);
    } else {
#pragma unroll
      for (int t = 0; t < 4; ++t)
        sr[t] = *(const uint4*)(Vw + (long)(t * 16 + (l >> 2)) * RS_ + R_ + kb + (l & 3) * 8);
    }
  };
  auto WRITE = [&](int bufi) {
    if (qsub == 0) {
      char* KT = pool + (bufi * 2 + half) * 4096;
#pragma unroll
      for (int t = 0; t < 4; ++t)
        *(uint4*)(KT + (t * 8 + (l >> 3)) * 128 + (((l & 7) ^ (l >> 3)) << 4)) = sr[t];
    } else {
      char* VT = pool + 16384 + (bufi * 2 + half) * 4096;
#pragma unroll
      for (int t = 0; t < 4; ++t)
        *(uint4*)(VT + (t * 16 + (l >> 2)) * 64 + (((l & 3) ^ ((l >> 3) & 3)) << 4)) = sr[t];
    }
  };

  LOAD(kb0);  // chunk 0 in flight during fuzzy branch

  // ---- fuzzy branch (half==0 waves, one per qsub), exp2 domain
  if (half == 0) {
    bf16x8 qsq0, qsq1, qbf0, qbf1;
#pragma unroll
    for (int j = 0; j < 8; ++j) {
      float a0 = (float)qa0[j], a1 = (float)qa1[j];
      qbf0[j] = (__bf16)a0;
      qbf1[j] = (__bf16)a1;
      qsq0[j] = (__bf16)(a0 * a0);
      qsq1[j] = (__bf16)(a1 * a1);
    }
    f32x4 z[2];
#pragma unroll
    for (int t = 0; t < 2; ++t) {
#pragma unroll
      for (int j = 0; j < 4; ++j) z[t][j] = cb[h * R_ + t * 16 + g * 4 + j];
      const __bf16* w1p = W1b + ((long)h * R_ + t * 16 + lo) * 64;
      const __bf16* w2p = W2b + ((long)h * R_ + t * 16 + lo) * 64;
      bf16x8 b10 = *(const bf16x8*)(w1p + g * 8);
      bf16x8 b11 = *(const bf16x8*)(w1p + 32 + g * 8);
      bf16x8 b20 = *(const bf16x8*)(w2p + g * 8);
      bf16x8 b21 = *(const bf16x8*)(w2p + 32 + g * 8);
      z[t] = mbf(b10, qsq0, z[t]);
      z[t] = mbf(b11, qsq1, z[t]);
      z[t] = mbf(b20, qbf0, z[t]);
      z[t] = mbf(b21, qbf1, z[t]);
    }
    float zm = z[0][0];
#pragma unroll
    for (int j = 1; j < 4; ++j) zm = fmaxf(zm, z[0][j]);
#pragma unroll
    for (int j = 0; j < 4; ++j) zm = fmaxf(zm, z[1][j]);
    zm = fmaxf(zm, __shfl_xor(zm, 16));
    zm = fmaxf(zm, __shfl_xor(zm, 32));
    float ez[2][4], zsum = 0.f;
#pragma unroll
    for (int t = 0; t < 2; ++t)
#pragma unroll
      for (int j = 0; j < 4; ++j) { ez[t][j] = EXP2(z[t][j] - zm); zsum += ez[t][j]; }
    zsum += __shfl_xor(zsum, 16);
    zsum += __shfl_xor(zsum, 32);
    float zin = 1.0f / zsum;
#pragma unroll
    for (int t = 0; t < 2; ++t)
#pragma unroll
      for (int j = 0; j < 4; ++j)
        fww[lo * 40 + t * 16 + g * 4 + j] = (_Float16)(ez[t][j] * zin);
  }

  WRITE(0);
  __syncthreads();

  // ---- flash key loop: 16 chunks of 32 keys from LDS (double-buffered)
  f32x4 O[4];
#pragma unroll
  for (int dt = 0; dt < 4; ++dt)
#pragma unroll
    for (int j = 0; j < 4; ++j) O[dt][j] = 0.f;
  float m = -__builtin_inff();
  float ellp = 0.f;

  int sw70 = (g ^ (lo & 7)) << 4;
  int sw71 = (((4 | g) ^ (lo & 7)) << 4);
  int swv = (g ^ ((lo >> 1) & 3)) << 4;

  for (int c = 0; c < 16; ++c) {
    if (c < 15) LOAD(kb0 + (c + 1) * 32);  // issue-early

    char* KT = pool + ((c & 1) * 2 + half) * 4096;
    char* VT = pool + 16384 + ((c & 1) * 2 + half) * 4096;
    f16x8 kf00 = *(const f16x8*)(KT + lo * 128 + sw70);
    f16x8 kf01 = *(const f16x8*)(KT + lo * 128 + sw71);
    f16x8 kf10 = *(const f16x8*)(KT + (16 + lo) * 128 + sw70);
    f16x8 kf11 = *(const f16x8*)(KT + (16 + lo) * 128 + sw71);
    f16x8 va0 = *(const f16x8*)(VT + (0 * 16 + lo) * 64 + swv);
    f16x8 va1 = *(const f16x8*)(VT + (1 * 16 + lo) * 64 + swv);
    f16x8 va2 = *(const f16x8*)(VT + (2 * 16 + lo) * 64 + swv);
    f16x8 va3 = *(const f16x8*)(VT + (3 * 16 + lo) * 64 + swv);

    f32x4 e0, e1;
#pragma unroll
    for (int j = 0; j < 4; ++j) { e0[j] = 0.f; e1[j] = 0.f; }
    e0 = mf16(kf00, qa0, e0);  // e0[j]: key kb+g*4+j, q=lo (exp2 domain)
    e0 = mf16(kf01, qa1, e0);
    e1 = mf16(kf10, qa0, e1);  // keys kb+16+g*4+j
    e1 = mf16(kf11, qa1, e1);

    // speculative exps with stale m (overlaps the pmax reduce)
    float p0[4], p1[4];
#pragma unroll
    for (int j = 0; j < 4; ++j) {
      p0[j] = EXP2(e0[j] - m);
      p1[j] = EXP2(e1[j] - m);
    }
    float pmax = e0[0];
#pragma unroll
    for (int j = 1; j < 4; ++j) pmax = fmaxf(pmax, e0[j]);
#pragma unroll
    for (int j = 0; j < 4; ++j) pmax = fmaxf(pmax, e1[j]);
    pmax = fmaxf(pmax, __shfl_xor(pmax, 16));
    pmax = fmaxf(pmax, __shfl_xor(pmax, 32));
    if (__any(pmax > m + 11.5f)) {  // rescale needed (rare): redo
      float mn = fmaxf(m, pmax);
      float sc = EXP2(m - mn);
      ellp *= sc;
#pragma unroll
      for (int dt = 0; dt < 4; ++dt)
#pragma unroll
        for (int j = 0; j < 4; ++j) O[dt][j] *= sc;
#pragma unroll
      for (int j = 0; j < 4; ++j) {
        p0[j] = EXP2(e0[j] - mn);
        p1[j] = EXP2(e1[j] - mn);
      }
      m = mn;
    }
    float s8 = 0.f;
#pragma unroll
    for (int j = 0; j < 4; ++j) s8 += p0[j] + p1[j];
    ellp += s8;
    fp16x2 w0 = __builtin_amdgcn_cvt_pkrtz(p0[0], p0[1]);
    fp16x2 w1 = __builtin_amdgcn_cvt_pkrtz(p0[2], p0[3]);
    fp16x2 w2 = __builtin_amdgcn_cvt_pkrtz(p1[0], p1[1]);
    fp16x2 w3 = __builtin_amdgcn_cvt_pkrtz(p1[2], p1[3]);
    *(fp16x2*)(Plw + g * 4)      = w0;
    *(fp16x2*)(Plw + g * 4 + 2)  = w1;
    *(fp16x2*)(Plw + 16 + g * 4)     = w2;
    *(fp16x2*)(Plw + 16 + g * 4 + 2) = w3;
    f16x8 pb = *(const f16x8*)(Plw + g * 8);  // B-frag: row q=lo
    O[0] = mf16(va0, pb, O[0]);
    O[1] = mf16(va1, pb, O[1]);
    O[2] = mf16(va2, pb, O[2]);
    O[3] = mf16(va3, pb, O[3]);

    if (c < 15) WRITE((c + 1) & 1);  // write-late (vmcnt waits here)
    __syncthreads();
  }

  // per-wave ell: cross-g reduce
  float ell = ellp;
  ell += __shfl_xor(ell, 16);
  ell += __shfl_xor(ell, 32);

  // ---- merge the pair's two states (per-lane, q = lo); KT/VT now dead
  float* OBl  = (float*)pool;             // [qsub][64][17]
  float* Olds = (float*)(pool + 8704);    // [qsub][16][68]
  float* mrgM = (float*)(pool + 17408);   // [qsub][16]
  float* mrgL = (float*)(pool + 17536);

  if (half == 1) {
#pragma unroll
    for (int dt = 0; dt < 4; ++dt)
#pragma unroll
      for (int j = 0; j < 4; ++j)
        OBl[qsub * 1088 + (dt * 16 + g * 4 + j) * 17 + lo] = O[dt][j];
    if (l < 16) {
      mrgM[qsub * 16 + l] = m;
      mrgL[qsub * 16 + l] = ell;
    }
  }
  __syncthreads();
  if (half == 0) {
    float mB = mrgM[qsub * 16 + lo];
    float lB = mrgL[qsub * 16 + lo];
    float m12 = fmaxf(m, mB);
    float sA = EXP2(m - m12);
    float sB = EXP2(mB - m12);
    float iv = 1.0f / (ell * sA + lB * sB);
    float fA = sA * iv, fB = sB * iv;
#pragma unroll
    for (int dt = 0; dt < 4; ++dt)
#pragma unroll
      for (int j = 0; j < 4; ++j)
        O[dt][j] = O[dt][j] * fA +
                   OBl[qsub * 1088 + (dt * 16 + g * 4 + j) * 17 + lo] * fB;
    // rules contribution (already normalized)
    f16x8 fb = *(const f16x8*)(fww + lo * 40 + g * 8);
#pragma unroll
    for (int dt = 0; dt < 4; ++dt) {
      f16x8 va = *(const f16x8*)(Vw + (long)(dt * 16 + lo) * RS_ + g * 8);
      O[dt] = mf16(va, fb, O[dt]);
    }
#pragma unroll
    for (int dt = 0; dt < 4; ++dt)
#pragma unroll
      for (int j = 0; j < 4; ++j)
        Olds[qsub * 1088 + lo * 68 + dt * 16 + g * 4 + j] = O[dt][j];
  }
  __syncthreads();
  for (int idx = tid; idx < 2 * 16 * 64; idx += 256) {
    int pp = idx >> 10;
    int row = (idx >> 6) & 15;
    int col = idx & 63;
    AO[((long)(b * S_ + s0 + pp * 16 + row)) * E_ + h * 64 + col] =
        (_Float16)Olds[pp * 1088 + row * 68 + col];
  }
}

// ---------------------------------------------------------------------------
// Kernel 4: MFMA output projection. C[n,e] = sum_f AO16[n,f]*Wo[e,f] + bo[e].
// ---------------------------------------------------------------------------
__global__ __launch_bounds__(256) void out_proj_mfma(const _Float16* __restrict__ AO16,
                                                     const float* __restrict__ Wo,
                                                     const float* __restrict__ bo,
                                                     float* __restrict__ Out) {
  __shared__ alignas(16) _Float16 As[2][64][72];
  __shared__ alignas(16) _Float16 Bs[2][64][72];

  int tid = threadIdx.x;
  int blk = blockIdx.x;
  int et = blk % 12;
  int nt = blk / 12;
  int n0 = nt * 64, e0 = et * 64;
  int w = tid >> 6, l = tid & 63, lo = l & 15, g = l >> 4;
  int i = tid >> 2, part = tid & 3;

  const _Float16* aop = AO16 + (long)(n0 + i) * E_ + part * 16;
  const float* wop = Wo + (long)(e0 + i) * E_ + part * 16;

  f32x4 acc[4];
#pragma unroll
  for (int ns = 0; ns < 4; ++ns)
#pragma unroll
    for (int q = 0; q < 4; ++q) acc[ns][q] = 0.f;

  auto STAGE = [&](int kb, int bufi) {
    const uint4* ap4 = (const uint4*)(aop + kb);
    uint4 a0 = ap4[0], a1 = ap4[1];
    *(uint4*)&As[bufi][i][part * 16]     = a0;
    *(uint4*)&As[bufi][i][part * 16 + 8] = a1;
    const float4* p = (const float4*)(wop + kb);
    float4 x0 = p[0], x1 = p[1], x2 = p[2], x3 = p[3];
    *(f16x8*)&Bs[bufi][i][part * 16]     = cvt8(x0, x1);
    *(f16x8*)&Bs[bufi][i][part * 16 + 8] = cvt8(x2, x3);
  };

  STAGE(0, 0);
  __syncthreads();
  for (int k = 0; k < 12; ++k) {
    if (k < 11) STAGE((k + 1) * 64, (k + 1) & 1);
    int bi = k & 1;
#pragma unroll
    for (int kc = 0; kc < 2; ++kc) {
      f16x8 af = *(const f16x8*)&As[bi][w * 16 + lo][kc * 32 + g * 8];
#pragma unroll
      for (int ns = 0; ns < 4; ++ns) {
        f16x8 bf = *(const f16x8*)&Bs[bi][ns * 16 + lo][kc * 32 + g * 8];
        acc[ns] = mf16(af, bf, acc[ns]);
      }
    }
    __syncthreads();
  }

  float* Cs = (float*)&As[0][0][0];  // Cs[n][e], stride 69
#pragma unroll
  for (int ns = 0; ns < 4; ++ns)
#pragma unroll
    for (int reg = 0; reg < 4; ++reg)
      Cs[(w * 16 + g * 4 + reg) * 69 + ns * 16 + lo] = acc[ns][reg];
  __syncthreads();

  float tmp[16];
#pragma unroll
  for (int q = 0; q < 16; ++q)
    tmp[q] = Cs[i * 69 + part * 16 + q] + bo[e0 + part * 16 + q];
  float* outp = Out + (long)(n0 + i) * E_ + e0 + part * 16;
#pragma unroll
  for (int q4 = 0; q4 < 4; ++q4)
    ((float4*)outp)[q4] = make_float4(tmp[q4 * 4], tmp[q4 * 4 + 1], tmp[q4 * 4 + 2], tmp[q4 * 4 + 3]);
}

extern "C" void kernel_launch(void* const* d_in, const int* in_sizes, int n_in,
                              void* d_out, int out_size, void* d_ws, size_t ws_size,
                              hipStream_t stream) {
  const float* query = (const float*)d_in[0];
  const float* key   = (const float*)d_in[1];
  const float* value = (const float*)d_in[2];
  const float* rk    = (const float*)d_in[3];
  const float* rw    = (const float*)d_in[4];
  const float* Wq    = (const float*)d_in[5];
  const float* Wk    = (const float*)d_in[6];
  const float* Wv    = (const float*)d_in[7];
  const float* bv    = (const float*)d_in[8];
  const float* Wo    = (const float*)d_in[9];
  const float* bo    = (const float*)d_in[10];
  float* out = (float*)d_out;

  char* wsb = (char*)d_ws;
  _Float16* Qh   = (_Float16*)(wsb);                 // 3,145,728 B
  _Float16* Kh   = (_Float16*)(wsb + 3145728);       // 3,145,728 B
  _Float16* VPT  = (_Float16*)(wsb + 6291456);       // 3,244,032 B
  _Float16* AO16 = (_Float16*)(wsb + 9535488);       // 3,145,728 B
  __bf16* W1b = (__bf16*)(wsb + 12681216);           // 49,152 B
  __bf16* W2b = (__bf16*)(wsb + 12730368);           // 49,152 B
  float* cb   = (float*)(wsb + 12779520);            // 1,536 B

  prep_rules<<<384, 64, 0, stream>>>(rk, rw, W1b, W2b, cb);
  qk_proj_mfma<<<384, 256, 0, stream>>>(query, key, Wq, Wk, Qh, Kh);
  v_proj_mfma<<<2 * 17 * 12, 256, 0, stream>>>(Wv, bv, value, VPT);
  attn_mfma<<<768, 256, 0, stream>>>(Qh, Kh, VPT, W1b, W2b, cb, AO16);
  out_proj_mfma<<<32 * 12, 256, 0, stream>>>(AO16, Wo, bo, out);
}

// Round 14
// 100.314 us; speedup vs baseline: 1.1785x; 1.1785x over previous
//
#include <hip/hip_runtime.h>

#define S_ 1024
#define E_ 768
#define H_ 12
#define R_ 32
#define D_ 64
#define RS_ 1056  // R_+S_

// exp2-domain constants: L = log2(e), LN2 = 1/L
#define L2E 1.4426950408889634f
#define LN2F 0.6931471805599453f

#if __has_builtin(__builtin_amdgcn_exp2f)
#define EXP2(x) __builtin_amdgcn_exp2f(x)
#else
#define EXP2(x) exp2f(x)
#endif

typedef _Float16 f16x8 __attribute__((ext_vector_type(8)));
typedef __fp16   fp16x2 __attribute__((ext_vector_type(2)));  // cvt_pkrtz return type
typedef __bf16   bf16x8 __attribute__((ext_vector_type(8)));
typedef float    f32x4 __attribute__((ext_vector_type(4)));

__device__ __forceinline__ f32x4 mf16(f16x8 a, f16x8 b, f32x4 c) {
  return __builtin_amdgcn_mfma_f32_16x16x32_f16(a, b, c, 0, 0, 0);
}
__device__ __forceinline__ f32x4 mbf(bf16x8 a, bf16x8 b, f32x4 c) {
  return __builtin_amdgcn_mfma_f32_16x16x32_bf16(a, b, c, 0, 0, 0);
}
__device__ __forceinline__ f16x8 cvt8(float4 a, float4 b) {
  f16x8 r;
  r[0] = (_Float16)a.x; r[1] = (_Float16)a.y; r[2] = (_Float16)a.z; r[3] = (_Float16)a.w;
  r[4] = (_Float16)b.x; r[5] = (_Float16)b.y; r[6] = (_Float16)b.z; r[7] = (_Float16)b.w;
  return r;
}

// ---------------------------------------------------------------------------
// Prep: fold fuzzy quadratic form into GEMM operands, exp2 domain.
// ---------------------------------------------------------------------------
__global__ __launch_bounds__(64) void prep_rules(const float* __restrict__ RK,
                                                 const float* __restrict__ RW,
                                                 __bf16* __restrict__ W1b,
                                                 __bf16* __restrict__ W2b,
                                                 float* __restrict__ cb) {
  int hr = blockIdx.x;  // 0..383 = h*32 + r
  int d = threadIdx.x;
  long idx = (long)hr * 64 + d;
  float w = RW[idx];
  float wi = 1.0f / w;
  float w2 = wi * wi;
  float rk = RK[idx];
  W1b[idx] = (__bf16)(-w2 * (LN2F / 524288.0f));
  W2b[idx] = (__bf16)(rk * w2 * (1.0f / 4096.0f));
  float part = rk * rk * w2;
  part += __shfl_xor(part, 1);
  part += __shfl_xor(part, 2);
  part += __shfl_xor(part, 4);
  part += __shfl_xor(part, 8);
  part += __shfl_xor(part, 16);
  part += __shfl_xor(part, 32);
  if (d == 0) cb[hr] = -part * (L2E / 128.0f);
}

// ---------------------------------------------------------------------------
// Kernel 1: per-head Q/K projections via MFMA, zero LDS. Q scaled 8*log2(e).
// ---------------------------------------------------------------------------
__global__ __launch_bounds__(256) void qk_proj_mfma(const float* __restrict__ query,
                                                    const float* __restrict__ key,
                                                    const float* __restrict__ Wq,
                                                    const float* __restrict__ Wk,
                                                    _Float16* __restrict__ Qh,
                                                    _Float16* __restrict__ Kh) {
  int blk = blockIdx.x;
  int st = blk & 15;
  int h  = (blk >> 4) % H_;
  int b  = blk / (16 * H_);
  int tid = threadIdx.x;
  int w = tid >> 6, l = tid & 63, lo = l & 15, g = l >> 4;

  int s_in = st * 64 + w * 16 + lo;
  const float* qp = query + ((long)(b * S_) + s_in) * E_ + h * 64;
  const float* kp = key   + ((long)(b * S_) + s_in) * E_ + h * 64;
  float4 a0 = *(const float4*)(qp + g * 8);
  float4 a1 = *(const float4*)(qp + g * 8 + 4);
  float4 a2 = *(const float4*)(qp + 32 + g * 8);
  float4 a3 = *(const float4*)(qp + 32 + g * 8 + 4);
  f16x8 xq0 = cvt8(a0, a1), xq1 = cvt8(a2, a3);
  a0 = *(const float4*)(kp + g * 8);
  a1 = *(const float4*)(kp + g * 8 + 4);
  a2 = *(const float4*)(kp + 32 + g * 8);
  a3 = *(const float4*)(kp + 32 + g * 8 + 4);
  f16x8 xk0 = cvt8(a0, a1), xk1 = cvt8(a2, a3);

  f32x4 accq[4], acck[4];
#pragma unroll
  for (int ns = 0; ns < 4; ++ns)
#pragma unroll
    for (int q = 0; q < 4; ++q) { accq[ns][q] = 0.f; acck[ns][q] = 0.f; }

#pragma unroll
  for (int ns = 0; ns < 4; ++ns) {
    const float* wqp = Wq + (long)(ns * 16 + lo) * 64;
    const float* wkp = Wk + (long)(ns * 16 + lo) * 64;
    float4 b0 = *(const float4*)(wqp + g * 8);
    float4 b1 = *(const float4*)(wqp + g * 8 + 4);
    float4 b2 = *(const float4*)(wqp + 32 + g * 8);
    float4 b3 = *(const float4*)(wqp + 32 + g * 8 + 4);
    f16x8 bq0 = cvt8(b0, b1), bq1 = cvt8(b2, b3);
    b0 = *(const float4*)(wkp + g * 8);
    b1 = *(const float4*)(wkp + g * 8 + 4);
    b2 = *(const float4*)(wkp + 32 + g * 8);
    b3 = *(const float4*)(wkp + 32 + g * 8 + 4);
    f16x8 bk0 = cvt8(b0, b1), bk1 = cvt8(b2, b3);
    accq[ns] = mf16(xq0, bq0, accq[ns]);
    accq[ns] = mf16(xq1, bq1, accq[ns]);
    acck[ns] = mf16(xk0, bk0, acck[ns]);
    acck[ns] = mf16(xk1, bk1, acck[ns]);
  }

  long rowbase = (long)(b * H_ + h) * S_ + st * 64 + w * 16;
#pragma unroll
  for (int ns = 0; ns < 4; ++ns) {
#pragma unroll
    for (int reg = 0; reg < 4; ++reg) {
      long off = (rowbase + g * 4 + reg) * 64 + ns * 16 + lo;
      Qh[off] = (_Float16)(accq[ns][reg] * (8.0f * L2E));
      Kh[off] = (_Float16)acck[ns][reg];
    }
  }
}

// ---------------------------------------------------------------------------
// Kernel 2a: transpose value -> VT16[b][e][s] f16 ([2][768][1024]).
// All-vector staging: uint4 LDS writes + f16x8 column-gather + uint4 stores.
// ---------------------------------------------------------------------------
__global__ __launch_bounds__(256) void vT(const float* __restrict__ value,
                                          _Float16* __restrict__ VT) {
  __shared__ alignas(16) _Float16 Ls[64][72];
  int blk = blockIdx.x;
  int et = blk % 12;
  int st = (blk / 12) % 16;
  int b = blk / (12 * 16);
  int s0 = st * 64, e0 = et * 64;
  int tid = threadIdx.x;
  int j = tid >> 2, part = tid & 3;

  const float4* p = (const float4*)(value + ((long)(b * S_ + s0 + j)) * E_ + e0 + part * 16);
  float4 x0 = p[0], x1 = p[1], x2 = p[2], x3 = p[3];
  *(f16x8*)&Ls[j][part * 16]     = cvt8(x0, x1);
  *(f16x8*)&Ls[j][part * 16 + 8] = cvt8(x2, x3);
  __syncthreads();

  int i = tid >> 2;  // local e row
  f16x8 o0, o1;
#pragma unroll
  for (int q = 0; q < 8; ++q) o0[q] = Ls[part * 16 + q][i];
#pragma unroll
  for (int q = 0; q < 8; ++q) o1[q] = Ls[part * 16 + 8 + q][i];
  _Float16* op = VT + ((long)(b * E_ + e0 + i)) * S_ + s0 + part * 16;
  *(f16x8*)op = o0;
  *((f16x8*)op + 1) = o1;
}

// ---------------------------------------------------------------------------
// Kernel 2b: MFMA value projection (both stages vectorized, reads VT).
// Per b: C[r,e] = sum_s Wv[r,s]*VT[b,e,s] -> VPT[b,h,d,r] = C + bv[r] (f16).
// ---------------------------------------------------------------------------
__global__ __launch_bounds__(256) void v_proj_mfma(const float* __restrict__ Wv,
                                                   const float* __restrict__ bv,
                                                   const _Float16* __restrict__ VT,
                                                   _Float16* __restrict__ VPT) {
  __shared__ alignas(16) _Float16 As[2][64][72];
  __shared__ alignas(16) _Float16 Bs[2][64][72];

  int tid = threadIdx.x;
  int blk = blockIdx.x;
  int et = blk % 12;
  int rt = (blk / 12) % 17;
  int b  = blk / (12 * 17);
  int r0 = rt * 64, e0 = et * 64;
  int w = tid >> 6, l = tid & 63, lo = l & 15, g = l >> 4;
  int i = tid >> 2, part = tid & 3;

  bool rvalid = (r0 + i) < RS_;
  const float* wvp = Wv + (long)(r0 + i) * S_ + part * 16;
  const _Float16* vtp = VT + ((long)(b * E_ + e0 + i)) * S_ + part * 16;

  f32x4 acc[4];
#pragma unroll
  for (int ns = 0; ns < 4; ++ns)
#pragma unroll
    for (int q = 0; q < 4; ++q) acc[ns][q] = 0.f;

  auto STAGE = [&](int kb, int bufi) {
    float4 x0, x1, x2, x3;
    if (rvalid) {
      const float4* p = (const float4*)(wvp + kb);
      x0 = p[0]; x1 = p[1]; x2 = p[2]; x3 = p[3];
    } else {
      x0 = x1 = x2 = x3 = make_float4(0.f, 0.f, 0.f, 0.f);
    }
    *(f16x8*)&As[bufi][i][part * 16]     = cvt8(x0, x1);
    *(f16x8*)&As[bufi][i][part * 16 + 8] = cvt8(x2, x3);
    const uint4* vp4 = (const uint4*)(vtp + kb);
    uint4 b0 = vp4[0], b1 = vp4[1];
    *(uint4*)&Bs[bufi][i][part * 16]     = b0;
    *(uint4*)&Bs[bufi][i][part * 16 + 8] = b1;
  };

  STAGE(0, 0);
  __syncthreads();
  for (int k = 0; k < 16; ++k) {
    if (k < 15) STAGE((k + 1) * 64, (k + 1) & 1);
    int bi = k & 1;
#pragma unroll
    for (int kc = 0; kc < 2; ++kc) {
      f16x8 af = *(const f16x8*)&As[bi][w * 16 + lo][kc * 32 + g * 8];
#pragma unroll
      for (int ns = 0; ns < 4; ++ns) {
        f16x8 bf = *(const f16x8*)&Bs[bi][ns * 16 + lo][kc * 32 + g * 8];
        acc[ns] = mf16(af, bf, acc[ns]);
      }
    }
    __syncthreads();
  }

  float bvr[4];
#pragma unroll
  for (int reg = 0; reg < 4; ++reg) {
    int r = r0 + w * 16 + g * 4 + reg;
    bvr[reg] = (r < RS_) ? bv[r] : 0.f;
  }
  float* Ct = (float*)&As[0][0][0];  // Ct[d][rloc], stride 69
#pragma unroll
  for (int ns = 0; ns < 4; ++ns)
#pragma unroll
    for (int reg = 0; reg < 4; ++reg)
      Ct[(ns * 16 + lo) * 69 + w * 16 + g * 4 + reg] = acc[ns][reg] + bvr[reg];
  __syncthreads();

  if (r0 + part * 16 < RS_) {
    f16x8 o0, o1;
#pragma unroll
    for (int q = 0; q < 8; ++q) o0[q] = (_Float16)Ct[i * 69 + part * 16 + q];
#pragma unroll
    for (int q = 0; q < 8; ++q) o1[q] = (_Float16)Ct[i * 69 + part * 16 + 8 + q];
    _Float16* op = VPT + ((long)((b * H_ + et) * 64 + i)) * RS_ + r0 + part * 16;
    *(f16x8*)op = o0;
    *((f16x8*)op + 1) = o1;
  }
}

// ---------------------------------------------------------------------------
// Kernel 3: MFMA flash attention, 32-row q-tile (2 q-subtiles x 2 key-halves),
// swapped QK^T, exp2 domain, speculative exp, direct global K/V loads.
// (Round-12 proven variant: 42.4 us.)  grid = B*H*32 = 768.
// ---------------------------------------------------------------------------
__global__ __launch_bounds__(256) void attn_mfma(
    const _Float16* __restrict__ Qh, const _Float16* __restrict__ Kh,
    const _Float16* __restrict__ VPT, const __bf16* __restrict__ W1b,
    const __bf16* __restrict__ W2b, const float* __restrict__ cb,
    _Float16* __restrict__ AO) {
  __shared__ alignas(16) _Float16 Plds[4][16][40];   // [wave][q=lo][key]
  __shared__ alignas(16) _Float16 fwlds[2][16][40];  // [qsub][q=lo][rule]
  __shared__ float OBl[2][64][17];                   // half==1 O spill per qsub
  __shared__ float mrgM[2][16];
  __shared__ float mrgL[2][16];
  __shared__ float Olds[2][16][68];

  int tid = threadIdx.x;
  int wv = tid >> 6;            // wave id
  int qsub = wv >> 1;           // 0/1: q-subtile
  int half = wv & 1;            // 0/1: key half
  int l = tid & 63;
  int lo = l & 15, g = l >> 4;

  int bh = blockIdx.x >> 5;
  int qt = blockIdx.x & 31;
  int b = bh / H_, h = bh % H_;
  int s0 = qt * 32;

  const _Float16* Qw = Qh + ((long)bh * S_ + s0 + qsub * 16) * 64;
  const _Float16* Kw = Kh + (long)bh * S_ * 64;
  const _Float16* Vw = VPT + (long)bh * 64 * RS_;

  f16x8 qa0 = *(const f16x8*)(Qw + (long)lo * 64 + g * 8);
  f16x8 qa1 = *(const f16x8*)(Qw + (long)lo * 64 + 32 + g * 8);

  // ---- fuzzy branch (half==0 waves, one per qsub), exp2 domain
  if (half == 0) {
    bf16x8 qsq0, qsq1, qbf0, qbf1;
#pragma unroll
    for (int j = 0; j < 8; ++j) {
      float a0 = (float)qa0[j], a1 = (float)qa1[j];
      qbf0[j] = (__bf16)a0;
      qbf1[j] = (__bf16)a1;
      qsq0[j] = (__bf16)(a0 * a0);
      qsq1[j] = (__bf16)(a1 * a1);
    }
    f32x4 z[2];
#pragma unroll
    for (int t = 0; t < 2; ++t) {
#pragma unroll
      for (int j = 0; j < 4; ++j) z[t][j] = cb[h * R_ + t * 16 + g * 4 + j];
      const __bf16* w1p = W1b + ((long)h * R_ + t * 16 + lo) * 64;
      const __bf16* w2p = W2b + ((long)h * R_ + t * 16 + lo) * 64;
      bf16x8 b10 = *(const bf16x8*)(w1p + g * 8);
      bf16x8 b11 = *(const bf16x8*)(w1p + 32 + g * 8);
      bf16x8 b20 = *(const bf16x8*)(w2p + g * 8);
      bf16x8 b21 = *(const bf16x8*)(w2p + 32 + g * 8);
      z[t] = mbf(b10, qsq0, z[t]);
      z[t] = mbf(b11, qsq1, z[t]);
      z[t] = mbf(b20, qbf0, z[t]);
      z[t] = mbf(b21, qbf1, z[t]);
    }
    float zm = z[0][0];
#pragma unroll
    for (int j = 1; j < 4; ++j) zm = fmaxf(zm, z[0][j]);
#pragma unroll
    for (int j = 0; j < 4; ++j) zm = fmaxf(zm, z[1][j]);
    zm = fmaxf(zm, __shfl_xor(zm, 16));
    zm = fmaxf(zm, __shfl_xor(zm, 32));
    float ez[2][4], zsum = 0.f;
#pragma unroll
    for (int t = 0; t < 2; ++t)
#pragma unroll
      for (int j = 0; j < 4; ++j) { ez[t][j] = EXP2(z[t][j] - zm); zsum += ez[t][j]; }
    zsum += __shfl_xor(zsum, 16);
    zsum += __shfl_xor(zsum, 32);
    float zin = 1.0f / zsum;
#pragma unroll
    for (int t = 0; t < 2; ++t)
#pragma unroll
      for (int j = 0; j < 4; ++j)
        fwlds[qsub][lo][t * 16 + g * 4 + j] = (_Float16)(ez[t][j] * zin);
  }

  // ---- flash key loop: 16 chunks of 32 keys (this wave's key half)
  f32x4 O[4];
#pragma unroll
  for (int dt = 0; dt < 4; ++dt)
#pragma unroll
    for (int j = 0; j < 4; ++j) O[dt][j] = 0.f;
  float m = -__builtin_inff();
  float ellp = 0.f;

  int kb0 = half * 512;
  const _Float16* kp0 = Kw + (long)(kb0 + lo) * 64 + g * 8;
  const _Float16* kp1 = Kw + (long)(kb0 + 16 + lo) * 64 + g * 8;
  f16x8 kf00 = *(const f16x8*)(kp0);
  f16x8 kf01 = *(const f16x8*)(kp0 + 32);
  f16x8 kf10 = *(const f16x8*)(kp1);
  f16x8 kf11 = *(const f16x8*)(kp1 + 32);

  for (int c = 0; c < 16; ++c) {
    int kb = kb0 + c * 32;
    f16x8 nf00, nf01, nf10, nf11;
    if (c < 15) {  // prefetch next chunk's K fragments
      const _Float16* np0 = Kw + (long)(kb + 32 + lo) * 64 + g * 8;
      const _Float16* np1 = Kw + (long)(kb + 48 + lo) * 64 + g * 8;
      nf00 = *(const f16x8*)(np0);
      nf01 = *(const f16x8*)(np0 + 32);
      nf10 = *(const f16x8*)(np1);
      nf11 = *(const f16x8*)(np1 + 32);
    }
    f32x4 e0, e1;
#pragma unroll
    for (int j = 0; j < 4; ++j) { e0[j] = 0.f; e1[j] = 0.f; }
    e0 = mf16(kf00, qa0, e0);  // e0[j]: key kb+g*4+j, q=lo (exp2 domain)
    e0 = mf16(kf01, qa1, e0);
    e1 = mf16(kf10, qa0, e1);  // keys kb+16+g*4+j
    e1 = mf16(kf11, qa1, e1);

    // issue V loads early (no dependence on e)
    f16x8 va0 = *(const f16x8*)(Vw + (long)(0 * 16 + lo) * RS_ + R_ + kb + g * 8);
    f16x8 va1 = *(const f16x8*)(Vw + (long)(1 * 16 + lo) * RS_ + R_ + kb + g * 8);
    f16x8 va2 = *(const f16x8*)(Vw + (long)(2 * 16 + lo) * RS_ + R_ + kb + g * 8);
    f16x8 va3 = *(const f16x8*)(Vw + (long)(3 * 16 + lo) * RS_ + R_ + kb + g * 8);

    // speculative exps with stale m (overlaps the pmax reduce)
    float p0[4], p1[4];
#pragma unroll
    for (int j = 0; j < 4; ++j) {
      p0[j] = EXP2(e0[j] - m);
      p1[j] = EXP2(e1[j] - m);
    }
    float pmax = e0[0];
#pragma unroll
    for (int j = 1; j < 4; ++j) pmax = fmaxf(pmax, e0[j]);
#pragma unroll
    for (int j = 0; j < 4; ++j) pmax = fmaxf(pmax, e1[j]);
    pmax = fmaxf(pmax, __shfl_xor(pmax, 16));
    pmax = fmaxf(pmax, __shfl_xor(pmax, 32));
    if (__any(pmax > m + 11.5f)) {  // rescale needed (rare): redo
      float mn = fmaxf(m, pmax);
      float sc = EXP2(m - mn);
      ellp *= sc;
#pragma unroll
      for (int dt = 0; dt < 4; ++dt)
#pragma unroll
        for (int j = 0; j < 4; ++j) O[dt][j] *= sc;
#pragma unroll
      for (int j = 0; j < 4; ++j) {
        p0[j] = EXP2(e0[j] - mn);
        p1[j] = EXP2(e1[j] - mn);
      }
      m = mn;
    }
    float s8 = 0.f;
#pragma unroll
    for (int j = 0; j < 4; ++j) s8 += p0[j] + p1[j];
    ellp += s8;
    // packed P write: 4 x b32 instead of 8 x b16
    fp16x2 w0 = __builtin_amdgcn_cvt_pkrtz(p0[0], p0[1]);
    fp16x2 w1 = __builtin_amdgcn_cvt_pkrtz(p0[2], p0[3]);
    fp16x2 w2 = __builtin_amdgcn_cvt_pkrtz(p1[0], p1[1]);
    fp16x2 w3 = __builtin_amdgcn_cvt_pkrtz(p1[2], p1[3]);
    *(fp16x2*)&Plds[wv][lo][g * 4]          = w0;
    *(fp16x2*)&Plds[wv][lo][g * 4 + 2]      = w1;
    *(fp16x2*)&Plds[wv][lo][16 + g * 4]     = w2;
    *(fp16x2*)&Plds[wv][lo][16 + g * 4 + 2] = w3;
    f16x8 pb = *(const f16x8*)&Plds[wv][lo][g * 8];  // B-frag: row q=lo
    O[0] = mf16(va0, pb, O[0]);
    O[1] = mf16(va1, pb, O[1]);
    O[2] = mf16(va2, pb, O[2]);
    O[3] = mf16(va3, pb, O[3]);
    kf00 = nf00; kf01 = nf01; kf10 = nf10; kf11 = nf11;
  }

  // per-wave ell: cross-g reduce
  float ell = ellp;
  ell += __shfl_xor(ell, 16);
  ell += __shfl_xor(ell, 32);

  // ---- merge the pair's two states (per-lane, q = lo)
  if (half == 1) {
#pragma unroll
    for (int dt = 0; dt < 4; ++dt)
#pragma unroll
      for (int j = 0; j < 4; ++j) OBl[qsub][dt * 16 + g * 4 + j][lo] = O[dt][j];
    if (l < 16) {
      mrgM[qsub][l] = m;
      mrgL[qsub][l] = ell;
    }
  }
  __syncthreads();
  if (half == 0) {
    float mB = mrgM[qsub][lo];
    float lB = mrgL[qsub][lo];
    float m12 = fmaxf(m, mB);
    float sA = EXP2(m - m12);
    float sB = EXP2(mB - m12);
    float iv = 1.0f / (ell * sA + lB * sB);
    float fA = sA * iv, fB = sB * iv;
#pragma unroll
    for (int dt = 0; dt < 4; ++dt)
#pragma unroll
      for (int j = 0; j < 4; ++j)
        O[dt][j] = O[dt][j] * fA + OBl[qsub][dt * 16 + g * 4 + j][lo] * fB;
    // rules contribution (already normalized)
    f16x8 fb = *(const f16x8*)&fwlds[qsub][lo][g * 8];
#pragma unroll
    for (int dt = 0; dt < 4; ++dt) {
      f16x8 va = *(const f16x8*)(Vw + (long)(dt * 16 + lo) * RS_ + g * 8);
      O[dt] = mf16(va, fb, O[dt]);
    }
#pragma unroll
    for (int dt = 0; dt < 4; ++dt)
#pragma unroll
      for (int j = 0; j < 4; ++j) Olds[qsub][lo][dt * 16 + g * 4 + j] = O[dt][j];
  }
  __syncthreads();
  for (int idx = tid; idx < 2 * 16 * 64; idx += 256) {
    int pp = idx >> 10;
    int row = (idx >> 6) & 15;
    int col = idx & 63;
    AO[((long)(b * S_ + s0 + pp * 16 + row)) * E_ + h * 64 + col] =
        (_Float16)Olds[pp][row][col];
  }
}

// ---------------------------------------------------------------------------
// Kernel 4: MFMA output projection. C[n,e] = sum_f AO16[n,f]*Wo[e,f] + bo[e].
// ---------------------------------------------------------------------------
__global__ __launch_bounds__(256) void out_proj_mfma(const _Float16* __restrict__ AO16,
                                                     const float* __restrict__ Wo,
                                                     const float* __restrict__ bo,
                                                     float* __restrict__ Out) {
  __shared__ alignas(16) _Float16 As[2][64][72];
  __shared__ alignas(16) _Float16 Bs[2][64][72];

  int tid = threadIdx.x;
  int blk = blockIdx.x;
  int et = blk % 12;
  int nt = blk / 12;
  int n0 = nt * 64, e0 = et * 64;
  int w = tid >> 6, l = tid & 63, lo = l & 15, g = l >> 4;
  int i = tid >> 2, part = tid & 3;

  const _Float16* aop = AO16 + (long)(n0 + i) * E_ + part * 16;
  const float* wop = Wo + (long)(e0 + i) * E_ + part * 16;

  f32x4 acc[4];
#pragma unroll
  for (int ns = 0; ns < 4; ++ns)
#pragma unroll
    for (int q = 0; q < 4; ++q) acc[ns][q] = 0.f;

  auto STAGE = [&](int kb, int bufi) {
    const uint4* ap4 = (const uint4*)(aop + kb);
    uint4 a0 = ap4[0], a1 = ap4[1];
    *(uint4*)&As[bufi][i][part * 16]     = a0;
    *(uint4*)&As[bufi][i][part * 16 + 8] = a1;
    const float4* p = (const float4*)(wop + kb);
    float4 x0 = p[0], x1 = p[1], x2 = p[2], x3 = p[3];
    *(f16x8*)&Bs[bufi][i][part * 16]     = cvt8(x0, x1);
    *(f16x8*)&Bs[bufi][i][part * 16 + 8] = cvt8(x2, x3);
  };

  STAGE(0, 0);
  __syncthreads();
  for (int k = 0; k < 12; ++k) {
    if (k < 11) STAGE((k + 1) * 64, (k + 1) & 1);
    int bi = k & 1;
#pragma unroll
    for (int kc = 0; kc < 2; ++kc) {
      f16x8 af = *(const f16x8*)&As[bi][w * 16 + lo][kc * 32 + g * 8];
#pragma unroll
      for (int ns = 0; ns < 4; ++ns) {
        f16x8 bf = *(const f16x8*)&Bs[bi][ns * 16 + lo][kc * 32 + g * 8];
        acc[ns] = mf16(af, bf, acc[ns]);
      }
    }
    __syncthreads();
  }

  float* Cs = (float*)&As[0][0][0];  // Cs[n][e], stride 69
#pragma unroll
  for (int ns = 0; ns < 4; ++ns)
#pragma unroll
    for (int reg = 0; reg < 4; ++reg)
      Cs[(w * 16 + g * 4 + reg) * 69 + ns * 16 + lo] = acc[ns][reg];
  __syncthreads();

  float tmp[16];
#pragma unroll
  for (int q = 0; q < 16; ++q)
    tmp[q] = Cs[i * 69 + part * 16 + q] + bo[e0 + part * 16 + q];
  float* outp = Out + (long)(n0 + i) * E_ + e0 + part * 16;
#pragma unroll
  for (int q4 = 0; q4 < 4; ++q4)
    ((float4*)outp)[q4] = make_float4(tmp[q4 * 4], tmp[q4 * 4 + 1], tmp[q4 * 4 + 2], tmp[q4 * 4 + 3]);
}

extern "C" void kernel_launch(void* const* d_in, const int* in_sizes, int n_in,
                              void* d_out, int out_size, void* d_ws, size_t ws_size,
                              hipStream_t stream) {
  const float* query = (const float*)d_in[0];
  const float* key   = (const float*)d_in[1];
  const float* value = (const float*)d_in[2];
  const float* rk    = (const float*)d_in[3];
  const float* rw    = (const float*)d_in[4];
  const float* Wq    = (const float*)d_in[5];
  const float* Wk    = (const float*)d_in[6];
  const float* Wv    = (const float*)d_in[7];
  const float* bv    = (const float*)d_in[8];
  const float* Wo    = (const float*)d_in[9];
  const float* bo    = (const float*)d_in[10];
  float* out = (float*)d_out;

  char* wsb = (char*)d_ws;
  _Float16* Qh   = (_Float16*)(wsb);                 // 3,145,728 B
  _Float16* Kh   = (_Float16*)(wsb + 3145728);       // 3,145,728 B
  _Float16* VPT  = (_Float16*)(wsb + 6291456);       // 3,244,032 B
  _Float16* VT   = (_Float16*)(wsb + 9535488);       // 3,145,728 B (aliased w/ AO16)
  _Float16* AO16 = VT;  // VT dead after v_proj_mfma; attn writes AO16 after
  __bf16* W1b = (__bf16*)(wsb + 12681216);           // 49,152 B
  __bf16* W2b = (__bf16*)(wsb + 12730368);           // 49,152 B
  float* cb   = (float*)(wsb + 12779520);            // 1,536 B

  prep_rules<<<384, 64, 0, stream>>>(rk, rw, W1b, W2b, cb);
  qk_proj_mfma<<<384, 256, 0, stream>>>(query, key, Wq, Wk, Qh, Kh);
  vT<<<2 * 16 * 12, 256, 0, stream>>>(value, VT);
  v_proj_mfma<<<2 * 17 * 12, 256, 0, stream>>>(Wv, bv, VT, VPT);
  attn_mfma<<<768, 256, 0, stream>>>(Qh, Kh, VPT, W1b, W2b, cb, AO16);
  out_proj_mfma<<<32 * 12, 256, 0, stream>>>(AO16, Wo, bo, out);
}

// Round 15
// 84.849 us; speedup vs baseline: 1.3933x; 1.1823x over previous
//
#include <hip/hip_runtime.h>

#define S_ 1024
#define E_ 768
#define H_ 12
#define R_ 32
#define D_ 64
#define RS_ 1056  // R_+S_

// exp2-domain constants: L = log2(e), LN2 = 1/L
#define L2E 1.4426950408889634f
#define LN2F 0.6931471805599453f

#if __has_builtin(__builtin_amdgcn_exp2f)
#define EXP2(x) __builtin_amdgcn_exp2f(x)
#else
#define EXP2(x) exp2f(x)
#endif

typedef _Float16 f16x8 __attribute__((ext_vector_type(8)));
typedef __fp16   fp16x2 __attribute__((ext_vector_type(2)));  // cvt_pkrtz return type
typedef __bf16   bf16x8 __attribute__((ext_vector_type(8)));
typedef float    f32x4 __attribute__((ext_vector_type(4)));

__device__ __forceinline__ f32x4 mf16(f16x8 a, f16x8 b, f32x4 c) {
  return __builtin_amdgcn_mfma_f32_16x16x32_f16(a, b, c, 0, 0, 0);
}
__device__ __forceinline__ f32x4 mbf(bf16x8 a, bf16x8 b, f32x4 c) {
  return __builtin_amdgcn_mfma_f32_16x16x32_bf16(a, b, c, 0, 0, 0);
}
__device__ __forceinline__ f16x8 cvt8(float4 a, float4 b) {
  f16x8 r;
  r[0] = (_Float16)a.x; r[1] = (_Float16)a.y; r[2] = (_Float16)a.z; r[3] = (_Float16)a.w;
  r[4] = (_Float16)b.x; r[5] = (_Float16)b.y; r[6] = (_Float16)b.z; r[7] = (_Float16)b.w;
  return r;
}

// ---------------------------------------------------------------------------
// Prep: fold fuzzy quadratic form into GEMM operands, exp2 domain.
// ---------------------------------------------------------------------------
__global__ __launch_bounds__(64) void prep_rules(const float* __restrict__ RK,
                                                 const float* __restrict__ RW,
                                                 __bf16* __restrict__ W1b,
                                                 __bf16* __restrict__ W2b,
                                                 float* __restrict__ cb) {
  int hr = blockIdx.x;  // 0..383 = h*32 + r
  int d = threadIdx.x;
  long idx = (long)hr * 64 + d;
  float w = RW[idx];
  float wi = 1.0f / w;
  float w2 = wi * wi;
  float rk = RK[idx];
  W1b[idx] = (__bf16)(-w2 * (LN2F / 524288.0f));
  W2b[idx] = (__bf16)(rk * w2 * (1.0f / 4096.0f));
  float part = rk * rk * w2;
  part += __shfl_xor(part, 1);
  part += __shfl_xor(part, 2);
  part += __shfl_xor(part, 4);
  part += __shfl_xor(part, 8);
  part += __shfl_xor(part, 16);
  part += __shfl_xor(part, 32);
  if (d == 0) cb[hr] = -part * (L2E / 128.0f);
}

// ---------------------------------------------------------------------------
// Kernel 1: per-head Q/K projections via MFMA, zero LDS. Q scaled 8*log2(e).
// K written TILED: KhT[bh][c=key/32][slice=d/8][key&31][8]  (2048 f16/chunk).
// ---------------------------------------------------------------------------
__global__ __launch_bounds__(256) void qk_proj_mfma(const float* __restrict__ query,
                                                    const float* __restrict__ key,
                                                    const float* __restrict__ Wq,
                                                    const float* __restrict__ Wk,
                                                    _Float16* __restrict__ Qh,
                                                    _Float16* __restrict__ KhT) {
  int blk = blockIdx.x;
  int st = blk & 15;
  int h  = (blk >> 4) % H_;
  int b  = blk / (16 * H_);
  int tid = threadIdx.x;
  int w = tid >> 6, l = tid & 63, lo = l & 15, g = l >> 4;

  int s_in = st * 64 + w * 16 + lo;
  const float* qp = query + ((long)(b * S_) + s_in) * E_ + h * 64;
  const float* kp = key   + ((long)(b * S_) + s_in) * E_ + h * 64;
  float4 a0 = *(const float4*)(qp + g * 8);
  float4 a1 = *(const float4*)(qp + g * 8 + 4);
  float4 a2 = *(const float4*)(qp + 32 + g * 8);
  float4 a3 = *(const float4*)(qp + 32 + g * 8 + 4);
  f16x8 xq0 = cvt8(a0, a1), xq1 = cvt8(a2, a3);
  a0 = *(const float4*)(kp + g * 8);
  a1 = *(const float4*)(kp + g * 8 + 4);
  a2 = *(const float4*)(kp + 32 + g * 8);
  a3 = *(const float4*)(kp + 32 + g * 8 + 4);
  f16x8 xk0 = cvt8(a0, a1), xk1 = cvt8(a2, a3);

  f32x4 accq[4], acck[4];
#pragma unroll
  for (int ns = 0; ns < 4; ++ns)
#pragma unroll
    for (int q = 0; q < 4; ++q) { accq[ns][q] = 0.f; acck[ns][q] = 0.f; }

#pragma unroll
  for (int ns = 0; ns < 4; ++ns) {
    const float* wqp = Wq + (long)(ns * 16 + lo) * 64;
    const float* wkp = Wk + (long)(ns * 16 + lo) * 64;
    float4 b0 = *(const float4*)(wqp + g * 8);
    float4 b1 = *(const float4*)(wqp + g * 8 + 4);
    float4 b2 = *(const float4*)(wqp + 32 + g * 8);
    float4 b3 = *(const float4*)(wqp + 32 + g * 8 + 4);
    f16x8 bq0 = cvt8(b0, b1), bq1 = cvt8(b2, b3);
    b0 = *(const float4*)(wkp + g * 8);
    b1 = *(const float4*)(wkp + g * 8 + 4);
    b2 = *(const float4*)(wkp + 32 + g * 8);
    b3 = *(const float4*)(wkp + 32 + g * 8 + 4);
    f16x8 bk0 = cvt8(b0, b1), bk1 = cvt8(b2, b3);
    accq[ns] = mf16(xq0, bq0, accq[ns]);
    accq[ns] = mf16(xq1, bq1, accq[ns]);
    acck[ns] = mf16(xk0, bk0, acck[ns]);
    acck[ns] = mf16(xk1, bk1, acck[ns]);
  }

  int bh = b * H_ + h;
  long rowbase = (long)bh * S_ + st * 64 + w * 16;
  long ktbase = (long)bh * 32 * 2048;
#pragma unroll
  for (int ns = 0; ns < 4; ++ns) {
#pragma unroll
    for (int reg = 0; reg < 4; ++reg) {
      int srow = st * 64 + w * 16 + g * 4 + reg;   // key index
      long qoff = (rowbase + g * 4 + reg) * 64 + ns * 16 + lo;
      Qh[qoff] = (_Float16)(accq[ns][reg] * (8.0f * L2E));
      // tiled K: chunk = srow>>5, slice = (ns*16+lo)>>3, key-in-chunk, elem
      long koff = ktbase + (long)(srow >> 5) * 2048 +
                  (ns * 2 + (lo >> 3)) * 256 + (srow & 31) * 8 + (lo & 7);
      KhT[koff] = (_Float16)acck[ns][reg];
    }
  }
}

// ---------------------------------------------------------------------------
// Kernel 2a: transpose value -> VT16[b][e][s] f16 ([2][768][1024]).
// ---------------------------------------------------------------------------
__global__ __launch_bounds__(256) void vT(const float* __restrict__ value,
                                          _Float16* __restrict__ VT) {
  __shared__ alignas(16) _Float16 Ls[64][72];
  int blk = blockIdx.x;
  int et = blk % 12;
  int st = (blk / 12) % 16;
  int b = blk / (12 * 16);
  int s0 = st * 64, e0 = et * 64;
  int tid = threadIdx.x;
  int j = tid >> 2, part = tid & 3;

  const float4* p = (const float4*)(value + ((long)(b * S_ + s0 + j)) * E_ + e0 + part * 16);
  float4 x0 = p[0], x1 = p[1], x2 = p[2], x3 = p[3];
  *(f16x8*)&Ls[j][part * 16]     = cvt8(x0, x1);
  *(f16x8*)&Ls[j][part * 16 + 8] = cvt8(x2, x3);
  __syncthreads();

  int i = tid >> 2;  // local e row
  f16x8 o0, o1;
#pragma unroll
  for (int q = 0; q < 8; ++q) o0[q] = Ls[part * 16 + q][i];
#pragma unroll
  for (int q = 0; q < 8; ++q) o1[q] = Ls[part * 16 + 8 + q][i];
  _Float16* op = VT + ((long)(b * E_ + e0 + i)) * S_ + s0 + part * 16;
  *(f16x8*)op = o0;
  *((f16x8*)op + 1) = o1;
}

// ---------------------------------------------------------------------------
// Kernel 2b: MFMA value projection (reads VT), output TILED:
// VPTt[bh][c=r/32][dt=d/16][lo=d&15][gs=(r&31)/8][8]  (2048 f16/chunk, 33 chunks).
// ---------------------------------------------------------------------------
__global__ __launch_bounds__(256) void v_proj_mfma(const float* __restrict__ Wv,
                                                   const float* __restrict__ bv,
                                                   const _Float16* __restrict__ VT,
                                                   _Float16* __restrict__ VPTt) {
  __shared__ alignas(16) _Float16 As[2][64][72];
  __shared__ alignas(16) _Float16 Bs[2][64][72];

  int tid = threadIdx.x;
  int blk = blockIdx.x;
  int et = blk % 12;
  int rt = (blk / 12) % 17;
  int b  = blk / (12 * 17);
  int r0 = rt * 64, e0 = et * 64;
  int w = tid >> 6, l = tid & 63, lo = l & 15, g = l >> 4;
  int i = tid >> 2, part = tid & 3;

  bool rvalid = (r0 + i) < RS_;
  const float* wvp = Wv + (long)(r0 + i) * S_ + part * 16;
  const _Float16* vtp = VT + ((long)(b * E_ + e0 + i)) * S_ + part * 16;

  f32x4 acc[4];
#pragma unroll
  for (int ns = 0; ns < 4; ++ns)
#pragma unroll
    for (int q = 0; q < 4; ++q) acc[ns][q] = 0.f;

  auto STAGE = [&](int kb, int bufi) {
    float4 x0, x1, x2, x3;
    if (rvalid) {
      const float4* p = (const float4*)(wvp + kb);
      x0 = p[0]; x1 = p[1]; x2 = p[2]; x3 = p[3];
    } else {
      x0 = x1 = x2 = x3 = make_float4(0.f, 0.f, 0.f, 0.f);
    }
    *(f16x8*)&As[bufi][i][part * 16]     = cvt8(x0, x1);
    *(f16x8*)&As[bufi][i][part * 16 + 8] = cvt8(x2, x3);
    const uint4* vp4 = (const uint4*)(vtp + kb);
    uint4 b0 = vp4[0], b1 = vp4[1];
    *(uint4*)&Bs[bufi][i][part * 16]     = b0;
    *(uint4*)&Bs[bufi][i][part * 16 + 8] = b1;
  };

  STAGE(0, 0);
  __syncthreads();
  for (int k = 0; k < 16; ++k) {
    if (k < 15) STAGE((k + 1) * 64, (k + 1) & 1);
    int bi = k & 1;
#pragma unroll
    for (int kc = 0; kc < 2; ++kc) {
      f16x8 af = *(const f16x8*)&As[bi][w * 16 + lo][kc * 32 + g * 8];
#pragma unroll
      for (int ns = 0; ns < 4; ++ns) {
        f16x8 bf = *(const f16x8*)&Bs[bi][ns * 16 + lo][kc * 32 + g * 8];
        acc[ns] = mf16(af, bf, acc[ns]);
      }
    }
    __syncthreads();
  }

  float bvr[4];
#pragma unroll
  for (int reg = 0; reg < 4; ++reg) {
    int r = r0 + w * 16 + g * 4 + reg;
    bvr[reg] = (r < RS_) ? bv[r] : 0.f;
  }
  float* Ct = (float*)&As[0][0][0];  // Ct[d][rloc], stride 69
#pragma unroll
  for (int ns = 0; ns < 4; ++ns)
#pragma unroll
    for (int reg = 0; reg < 4; ++reg)
      Ct[(ns * 16 + lo) * 69 + w * 16 + g * 4 + reg] = acc[ns][reg] + bvr[reg];
  __syncthreads();

  if (r0 + part * 16 < RS_) {
    f16x8 o0, o1;
#pragma unroll
    for (int q = 0; q < 8; ++q) o0[q] = (_Float16)Ct[i * 69 + part * 16 + q];
#pragma unroll
    for (int q = 0; q < 8; ++q) o1[q] = (_Float16)Ct[i * 69 + part * 16 + 8 + q];
    // tiled write: c = rt*2 + part/2, j = (part&1)*16 + q
    int dtv = i >> 4, lov = i & 15;
    int c = rt * 2 + (part >> 1);
    _Float16* op = VPTt + (long)(b * H_ + et) * 67584 + (long)c * 2048 +
                   dtv * 512 + lov * 32 + ((part & 1) * 2) * 8;
    *(f16x8*)op = o0;
    *((f16x8*)op + 1) = o1;
  }
}

// ---------------------------------------------------------------------------
// Kernel 3: MFMA flash attention, 32-row q-tile, swapped QK^T, exp2 domain,
// speculative exp; K/V loads from TILED layouts (coalesced). grid = 768.
// ---------------------------------------------------------------------------
__global__ __launch_bounds__(256) void attn_mfma(
    const _Float16* __restrict__ Qh, const _Float16* __restrict__ KhT,
    const _Float16* __restrict__ VPTt, const __bf16* __restrict__ W1b,
    const __bf16* __restrict__ W2b, const float* __restrict__ cb,
    _Float16* __restrict__ AO) {
  __shared__ alignas(16) _Float16 Plds[4][16][40];   // [wave][q=lo][key]
  __shared__ alignas(16) _Float16 fwlds[2][16][40];  // [qsub][q=lo][rule]
  __shared__ float OBl[2][64][17];                   // half==1 O spill per qsub
  __shared__ float mrgM[2][16];
  __shared__ float mrgL[2][16];
  __shared__ float Olds[2][16][68];

  int tid = threadIdx.x;
  int wv = tid >> 6;            // wave id
  int qsub = wv >> 1;           // 0/1: q-subtile
  int half = wv & 1;            // 0/1: key half
  int l = tid & 63;
  int lo = l & 15, g = l >> 4;

  int bh = blockIdx.x >> 5;
  int qt = blockIdx.x & 31;
  int b = bh / H_, h = bh % H_;
  int s0 = qt * 32;

  const _Float16* Qw = Qh + ((long)bh * S_ + s0 + qsub * 16) * 64;
  const _Float16* Kt = KhT + (long)bh * 65536;
  const _Float16* Vt = VPTt + (long)bh * 67584;

  f16x8 qa0 = *(const f16x8*)(Qw + (long)lo * 64 + g * 8);
  f16x8 qa1 = *(const f16x8*)(Qw + (long)lo * 64 + 32 + g * 8);

  // ---- fuzzy branch (half==0 waves, one per qsub), exp2 domain
  if (half == 0) {
    bf16x8 qsq0, qsq1, qbf0, qbf1;
#pragma unroll
    for (int j = 0; j < 8; ++j) {
      float a0 = (float)qa0[j], a1 = (float)qa1[j];
      qbf0[j] = (__bf16)a0;
      qbf1[j] = (__bf16)a1;
      qsq0[j] = (__bf16)(a0 * a0);
      qsq1[j] = (__bf16)(a1 * a1);
    }
    f32x4 z[2];
#pragma unroll
    for (int t = 0; t < 2; ++t) {
#pragma unroll
      for (int j = 0; j < 4; ++j) z[t][j] = cb[h * R_ + t * 16 + g * 4 + j];
      const __bf16* w1p = W1b + ((long)h * R_ + t * 16 + lo) * 64;
      const __bf16* w2p = W2b + ((long)h * R_ + t * 16 + lo) * 64;
      bf16x8 b10 = *(const bf16x8*)(w1p + g * 8);
      bf16x8 b11 = *(const bf16x8*)(w1p + 32 + g * 8);
      bf16x8 b20 = *(const bf16x8*)(w2p + g * 8);
      bf16x8 b21 = *(const bf16x8*)(w2p + 32 + g * 8);
      z[t] = mbf(b10, qsq0, z[t]);
      z[t] = mbf(b11, qsq1, z[t]);
      z[t] = mbf(b20, qbf0, z[t]);
      z[t] = mbf(b21, qbf1, z[t]);
    }
    float zm = z[0][0];
#pragma unroll
    for (int j = 1; j < 4; ++j) zm = fmaxf(zm, z[0][j]);
#pragma unroll
    for (int j = 0; j < 4; ++j) zm = fmaxf(zm, z[1][j]);
    zm = fmaxf(zm, __shfl_xor(zm, 16));
    zm = fmaxf(zm, __shfl_xor(zm, 32));
    float ez[2][4], zsum = 0.f;
#pragma unroll
    for (int t = 0; t < 2; ++t)
#pragma unroll
      for (int j = 0; j < 4; ++j) { ez[t][j] = EXP2(z[t][j] - zm); zsum += ez[t][j]; }
    zsum += __shfl_xor(zsum, 16);
    zsum += __shfl_xor(zsum, 32);
    float zin = 1.0f / zsum;
#pragma unroll
    for (int t = 0; t < 2; ++t)
#pragma unroll
      for (int j = 0; j < 4; ++j)
        fwlds[qsub][lo][t * 16 + g * 4 + j] = (_Float16)(ez[t][j] * zin);
  }

  // ---- flash key loop: 16 chunks of 32 keys (this wave's key half)
  f32x4 O[4];
#pragma unroll
  for (int dt = 0; dt < 4; ++dt)
#pragma unroll
    for (int j = 0; j < 4; ++j) O[dt][j] = 0.f;
  float m = -__builtin_inff();
  float ellp = 0.f;

  int cg0 = half * 16;
  const _Float16* kc0 = Kt + (long)(cg0 * 8 + g) * 256 + lo * 8;
  const _Float16* kc1 = Kt + (long)(cg0 * 8 + g + 4) * 256 + lo * 8;
  f16x8 kf00 = *(const f16x8*)(kc0);
  f16x8 kf01 = *(const f16x8*)(kc1);
  f16x8 kf10 = *(const f16x8*)(kc0 + 128);
  f16x8 kf11 = *(const f16x8*)(kc1 + 128);

  for (int c = 0; c < 16; ++c) {
    int cg = cg0 + c;
    f16x8 nf00, nf01, nf10, nf11;
    if (c < 15) {  // prefetch next chunk's K fragments (coalesced tiles)
      const _Float16* np0 = Kt + (long)((cg + 1) * 8 + g) * 256 + lo * 8;
      const _Float16* np1 = Kt + (long)((cg + 1) * 8 + g + 4) * 256 + lo * 8;
      nf00 = *(const f16x8*)(np0);
      nf01 = *(const f16x8*)(np1);
      nf10 = *(const f16x8*)(np0 + 128);
      nf11 = *(const f16x8*)(np1 + 128);
    }
    f32x4 e0, e1;
#pragma unroll
    for (int j = 0; j < 4; ++j) { e0[j] = 0.f; e1[j] = 0.f; }
    e0 = mf16(kf00, qa0, e0);  // e0[j]: key cg*32+g*4+j, q=lo (exp2 domain)
    e0 = mf16(kf01, qa1, e0);
    e1 = mf16(kf10, qa0, e1);  // keys cg*32+16+g*4+j
    e1 = mf16(kf11, qa1, e1);

    // issue V loads early (coalesced 1KB per instruction)
    const _Float16* vchunk = Vt + (long)(cg + 1) * 2048 + lo * 32 + g * 8;
    f16x8 va0 = *(const f16x8*)(vchunk);
    f16x8 va1 = *(const f16x8*)(vchunk + 512);
    f16x8 va2 = *(const f16x8*)(vchunk + 1024);
    f16x8 va3 = *(const f16x8*)(vchunk + 1536);

    // speculative exps with stale m (overlaps the pmax reduce)
    float p0[4], p1[4];
#pragma unroll
    for (int j = 0; j < 4; ++j) {
      p0[j] = EXP2(e0[j] - m);
      p1[j] = EXP2(e1[j] - m);
    }
    float pmax = e0[0];
#pragma unroll
    for (int j = 1; j < 4; ++j) pmax = fmaxf(pmax, e0[j]);
#pragma unroll
    for (int j = 0; j < 4; ++j) pmax = fmaxf(pmax, e1[j]);
    pmax = fmaxf(pmax, __shfl_xor(pmax, 16));
    pmax = fmaxf(pmax, __shfl_xor(pmax, 32));
    if (__any(pmax > m + 11.5f)) {  // rescale needed (rare): redo
      float mn = fmaxf(m, pmax);
      float sc = EXP2(m - mn);
      ellp *= sc;
#pragma unroll
      for (int dt = 0; dt < 4; ++dt)
#pragma unroll
        for (int j = 0; j < 4; ++j) O[dt][j] *= sc;
#pragma unroll
      for (int j = 0; j < 4; ++j) {
        p0[j] = EXP2(e0[j] - mn);
        p1[j] = EXP2(e1[j] - mn);
      }
      m = mn;
    }
    float s8 = 0.f;
#pragma unroll
    for (int j = 0; j < 4; ++j) s8 += p0[j] + p1[j];
    ellp += s8;
    // packed P write: 4 x b32
    fp16x2 w0 = __builtin_amdgcn_cvt_pkrtz(p0[0], p0[1]);
    fp16x2 w1 = __builtin_amdgcn_cvt_pkrtz(p0[2], p0[3]);
    fp16x2 w2 = __builtin_amdgcn_cvt_pkrtz(p1[0], p1[1]);
    fp16x2 w3 = __builtin_amdgcn_cvt_pkrtz(p1[2], p1[3]);
    *(fp16x2*)&Plds[wv][lo][g * 4]          = w0;
    *(fp16x2*)&Plds[wv][lo][g * 4 + 2]      = w1;
    *(fp16x2*)&Plds[wv][lo][16 + g * 4]     = w2;
    *(fp16x2*)&Plds[wv][lo][16 + g * 4 + 2] = w3;
    f16x8 pb = *(const f16x8*)&Plds[wv][lo][g * 8];  // B-frag: row q=lo
    O[0] = mf16(va0, pb, O[0]);
    O[1] = mf16(va1, pb, O[1]);
    O[2] = mf16(va2, pb, O[2]);
    O[3] = mf16(va3, pb, O[3]);
    kf00 = nf00; kf01 = nf01; kf10 = nf10; kf11 = nf11;
  }

  // per-wave ell: cross-g reduce
  float ell = ellp;
  ell += __shfl_xor(ell, 16);
  ell += __shfl_xor(ell, 32);

  // ---- merge the pair's two states (per-lane, q = lo)
  if (half == 1) {
#pragma unroll
    for (int dt = 0; dt < 4; ++dt)
#pragma unroll
      for (int j = 0; j < 4; ++j) OBl[qsub][dt * 16 + g * 4 + j][lo] = O[dt][j];
    if (l < 16) {
      mrgM[qsub][l] = m;
      mrgL[qsub][l] = ell;
    }
  }
  __syncthreads();
  if (half == 0) {
    float mB = mrgM[qsub][lo];
    float lB = mrgL[qsub][lo];
    float m12 = fmaxf(m, mB);
    float sA = EXP2(m - m12);
    float sB = EXP2(mB - m12);
    float iv = 1.0f / (ell * sA + lB * sB);
    float fA = sA * iv, fB = sB * iv;
#pragma unroll
    for (int dt = 0; dt < 4; ++dt)
#pragma unroll
      for (int j = 0; j < 4; ++j)
        O[dt][j] = O[dt][j] * fA + OBl[qsub][dt * 16 + g * 4 + j][lo] * fB;
    // rules contribution (chunk 0 of tiled V, already normalized)
    f16x8 fb = *(const f16x8*)&fwlds[qsub][lo][g * 8];
    const _Float16* vrules = Vt + lo * 32 + g * 8;
#pragma unroll
    for (int dt = 0; dt < 4; ++dt) {
      f16x8 va = *(const f16x8*)(vrules + dt * 512);
      O[dt] = mf16(va, fb, O[dt]);
    }
#pragma unroll
    for (int dt = 0; dt < 4; ++dt)
#pragma unroll
      for (int j = 0; j < 4; ++j) Olds[qsub][lo][dt * 16 + g * 4 + j] = O[dt][j];
  }
  __syncthreads();
  for (int idx = tid; idx < 2 * 16 * 64; idx += 256) {
    int pp = idx >> 10;
    int row = (idx >> 6) & 15;
    int col = idx & 63;
    AO[((long)(b * S_ + s0 + pp * 16 + row)) * E_ + h * 64 + col] =
        (_Float16)Olds[pp][row][col];
  }
}

// ---------------------------------------------------------------------------
// Kernel 4: MFMA output projection. C[n,e] = sum_f AO16[n,f]*Wo[e,f] + bo[e].
// ---------------------------------------------------------------------------
__global__ __launch_bounds__(256) void out_proj_mfma(const _Float16* __restrict__ AO16,
                                                     const float* __restrict__ Wo,
                                                     const float* __restrict__ bo,
                                                     float* __restrict__ Out) {
  __shared__ alignas(16) _Float16 As[2][64][72];
  __shared__ alignas(16) _Float16 Bs[2][64][72];

  int tid = threadIdx.x;
  int blk = blockIdx.x;
  int et = blk % 12;
  int nt = blk / 12;
  int n0 = nt * 64, e0 = et * 64;
  int w = tid >> 6, l = tid & 63, lo = l & 15, g = l >> 4;
  int i = tid >> 2, part = tid & 3;

  const _Float16* aop = AO16 + (long)(n0 + i) * E_ + part * 16;
  const float* wop = Wo + (long)(e0 + i) * E_ + part * 16;

  f32x4 acc[4];
#pragma unroll
  for (int ns = 0; ns < 4; ++ns)
#pragma unroll
    for (int q = 0; q < 4; ++q) acc[ns][q] = 0.f;

  auto STAGE = [&](int kb, int bufi) {
    const uint4* ap4 = (const uint4*)(aop + kb);
    uint4 a0 = ap4[0], a1 = ap4[1];
    *(uint4*)&As[bufi][i][part * 16]     = a0;
    *(uint4*)&As[bufi][i][part * 16 + 8] = a1;
    const float4* p = (const float4*)(wop + kb);
    float4 x0 = p[0], x1 = p[1], x2 = p[2], x3 = p[3];
    *(f16x8*)&Bs[bufi][i][part * 16]     = cvt8(x0, x1);
    *(f16x8*)&Bs[bufi][i][part * 16 + 8] = cvt8(x2, x3);
  };

  STAGE(0, 0);
  __syncthreads();
  for (int k = 0; k < 12; ++k) {
    if (k < 11) STAGE((k + 1) * 64, (k + 1) & 1);
    int bi = k & 1;
#pragma unroll
    for (int kc = 0; kc < 2; ++kc) {
      f16x8 af = *(const f16x8*)&As[bi][w * 16 + lo][kc * 32 + g * 8];
#pragma unroll
      for (int ns = 0; ns < 4; ++ns) {
        f16x8 bf = *(const f16x8*)&Bs[bi][ns * 16 + lo][kc * 32 + g * 8];
        acc[ns] = mf16(af, bf, acc[ns]);
      }
    }
    __syncthreads();
  }

  float* Cs = (float*)&As[0][0][0];  // Cs[n][e], stride 69
#pragma unroll
  for (int ns = 0; ns < 4; ++ns)
#pragma unroll
    for (int reg = 0; reg < 4; ++reg)
      Cs[(w * 16 + g * 4 + reg) * 69 + ns * 16 + lo] = acc[ns][reg];
  __syncthreads();

  float tmp[16];
#pragma unroll
  for (int q = 0; q < 16; ++q)
    tmp[q] = Cs[i * 69 + part * 16 + q] + bo[e0 + part * 16 + q];
  float* outp = Out + (long)(n0 + i) * E_ + e0 + part * 16;
#pragma unroll
  for (int q4 = 0; q4 < 4; ++q4)
    ((float4*)outp)[q4] = make_float4(tmp[q4 * 4], tmp[q4 * 4 + 1], tmp[q4 * 4 + 2], tmp[q4 * 4 + 3]);
}

extern "C" void kernel_launch(void* const* d_in, const int* in_sizes, int n_in,
                              void* d_out, int out_size, void* d_ws, size_t ws_size,
                              hipStream_t stream) {
  const float* query = (const float*)d_in[0];
  const float* key   = (const float*)d_in[1];
  const float* value = (const float*)d_in[2];
  const float* rk    = (const float*)d_in[3];
  const float* rw    = (const float*)d_in[4];
  const float* Wq    = (const float*)d_in[5];
  const float* Wk    = (const float*)d_in[6];
  const float* Wv    = (const float*)d_in[7];
  const float* bv    = (const float*)d_in[8];
  const float* Wo    = (const float*)d_in[9];
  const float* bo    = (const float*)d_in[10];
  float* out = (float*)d_out;

  char* wsb = (char*)d_ws;
  _Float16* Qh   = (_Float16*)(wsb);                 // 3,145,728 B
  _Float16* KhT  = (_Float16*)(wsb + 3145728);       // 3,145,728 B (tiled)
  _Float16* VPTt = (_Float16*)(wsb + 6291456);       // 3,244,032 B (tiled)
  _Float16* VT   = (_Float16*)(wsb + 9535488);       // 3,145,728 B (aliased w/ AO16)
  _Float16* AO16 = VT;  // VT dead after v_proj_mfma; attn writes AO16 after
  __bf16* W1b = (__bf16*)(wsb + 12681216);           // 49,152 B
  __bf16* W2b = (__bf16*)(wsb + 12730368);           // 49,152 B
  float* cb   = (float*)(wsb + 12779520);            // 1,536 B

  prep_rules<<<384, 64, 0, stream>>>(rk, rw, W1b, W2b, cb);
  qk_proj_mfma<<<384, 256, 0, stream>>>(query, key, Wq, Wk, Qh, KhT);
  vT<<<2 * 16 * 12, 256, 0, stream>>>(value, VT);
  v_proj_mfma<<<2 * 17 * 12, 256, 0, stream>>>(Wv, bv, VT, VPTt);
  attn_mfma<<<768, 256, 0, stream>>>(Qh, KhT, VPTt, W1b, W2b, cb, AO16);
  out_proj_mfma<<<32 * 12, 256, 0, stream>>>(AO16, Wo, bo, out);
}

// Round 17
// 76.795 us; speedup vs baseline: 1.5395x; 1.1049x over previous
//
#include <hip/hip_runtime.h>

#define S_ 1024
#define E_ 768
#define H_ 12
#define R_ 32
#define D_ 64
#define RS_ 1056  // R_+S_

// exp2-domain constants: L = log2(e), LN2 = 1/L
#define L2E 1.4426950408889634f
#define LN2F 0.6931471805599453f

#if __has_builtin(__builtin_amdgcn_exp2f)
#define EXP2(x) __builtin_amdgcn_exp2f(x)
#else
#define EXP2(x) exp2f(x)
#endif

typedef _Float16 f16x8 __attribute__((ext_vector_type(8)));
typedef __fp16   fp16x2 __attribute__((ext_vector_type(2)));  // cvt_pkrtz return type
typedef __bf16   bf16x8 __attribute__((ext_vector_type(8)));
typedef float    f32x4 __attribute__((ext_vector_type(4)));

__device__ __forceinline__ f32x4 mf16(f16x8 a, f16x8 b, f32x4 c) {
  return __builtin_amdgcn_mfma_f32_16x16x32_f16(a, b, c, 0, 0, 0);
}
__device__ __forceinline__ f32x4 mbf(bf16x8 a, bf16x8 b, f32x4 c) {
  return __builtin_amdgcn_mfma_f32_16x16x32_bf16(a, b, c, 0, 0, 0);
}
__device__ __forceinline__ f16x8 cvt8(float4 a, float4 b) {
  f16x8 r;
  r[0] = (_Float16)a.x; r[1] = (_Float16)a.y; r[2] = (_Float16)a.z; r[3] = (_Float16)a.w;
  r[4] = (_Float16)b.x; r[5] = (_Float16)b.y; r[6] = (_Float16)b.z; r[7] = (_Float16)b.w;
  return r;
}

// ---------------------------------------------------------------------------
// Fused front-end: blocks [0,384) qk_proj, [384,768) vT, [768,864) prep_rules.
// All three are mutually independent; fusing fills the GPU and cuts launches.
// ---------------------------------------------------------------------------
__global__ __launch_bounds__(256) void frontend(
    const float* __restrict__ query, const float* __restrict__ key,
    const float* __restrict__ Wq, const float* __restrict__ Wk,
    const float* __restrict__ value, const float* __restrict__ RK,
    const float* __restrict__ RW, _Float16* __restrict__ Qh,
    _Float16* __restrict__ KhT, _Float16* __restrict__ VT,
    __bf16* __restrict__ W1b, __bf16* __restrict__ W2b,
    float* __restrict__ cb) {
  __shared__ alignas(16) _Float16 Ls[64][72];
  int blk0 = blockIdx.x;
  int tid = threadIdx.x;

  if (blk0 < 384) {
    // ---- qk_proj: per-head Q/K projections via MFMA. Q scaled 8*log2(e).
    // K written TILED: KhT[bh][c=key/32][slice=d/8][key&31][8].
    int blk = blk0;
    int st = blk & 15;
    int h  = (blk >> 4) % H_;
    int b  = blk / (16 * H_);
    int w = tid >> 6, l = tid & 63, lo = l & 15, g = l >> 4;

    int s_in = st * 64 + w * 16 + lo;
    const float* qp = query + ((long)(b * S_) + s_in) * E_ + h * 64;
    const float* kp = key   + ((long)(b * S_) + s_in) * E_ + h * 64;
    float4 a0 = *(const float4*)(qp + g * 8);
    float4 a1 = *(const float4*)(qp + g * 8 + 4);
    float4 a2 = *(const float4*)(qp + 32 + g * 8);
    float4 a3 = *(const float4*)(qp + 32 + g * 8 + 4);
    f16x8 xq0 = cvt8(a0, a1), xq1 = cvt8(a2, a3);
    a0 = *(const float4*)(kp + g * 8);
    a1 = *(const float4*)(kp + g * 8 + 4);
    a2 = *(const float4*)(kp + 32 + g * 8);
    a3 = *(const float4*)(kp + 32 + g * 8 + 4);
    f16x8 xk0 = cvt8(a0, a1), xk1 = cvt8(a2, a3);

    f32x4 accq[4], acck[4];
#pragma unroll
    for (int ns = 0; ns < 4; ++ns)
#pragma unroll
      for (int q = 0; q < 4; ++q) { accq[ns][q] = 0.f; acck[ns][q] = 0.f; }

#pragma unroll
    for (int ns = 0; ns < 4; ++ns) {
      const float* wqp = Wq + (long)(ns * 16 + lo) * 64;
      const float* wkp = Wk + (long)(ns * 16 + lo) * 64;
      float4 b0 = *(const float4*)(wqp + g * 8);
      float4 b1 = *(const float4*)(wqp + g * 8 + 4);
      float4 b2 = *(const float4*)(wqp + 32 + g * 8);
      float4 b3 = *(const float4*)(wqp + 32 + g * 8 + 4);
      f16x8 bq0 = cvt8(b0, b1), bq1 = cvt8(b2, b3);
      b0 = *(const float4*)(wkp + g * 8);
      b1 = *(const float4*)(wkp + g * 8 + 4);
      b2 = *(const float4*)(wkp + 32 + g * 8);
      b3 = *(const float4*)(wkp + 32 + g * 8 + 4);
      f16x8 bk0 = cvt8(b0, b1), bk1 = cvt8(b2, b3);
      accq[ns] = mf16(xq0, bq0, accq[ns]);
      accq[ns] = mf16(xq1, bq1, accq[ns]);
      acck[ns] = mf16(xk0, bk0, acck[ns]);
      acck[ns] = mf16(xk1, bk1, acck[ns]);
    }

    int bh = b * H_ + h;
    long rowbase = (long)bh * S_ + st * 64 + w * 16;
    long ktbase = (long)bh * 32 * 2048;
#pragma unroll
    for (int ns = 0; ns < 4; ++ns) {
#pragma unroll
      for (int reg = 0; reg < 4; ++reg) {
        int srow = st * 64 + w * 16 + g * 4 + reg;   // key index
        long qoff = (rowbase + g * 4 + reg) * 64 + ns * 16 + lo;
        Qh[qoff] = (_Float16)(accq[ns][reg] * (8.0f * L2E));
        long koff = ktbase + (long)(srow >> 5) * 2048 +
                    (ns * 2 + (lo >> 3)) * 256 + (srow & 31) * 8 + (lo & 7);
        KhT[koff] = (_Float16)acck[ns][reg];
      }
    }
  } else if (blk0 < 768) {
    // ---- vT: transpose value -> VT16[b][e][s] f16.
    int blk = blk0 - 384;
    int et = blk % 12;
    int st = (blk / 12) % 16;
    int b = blk / (12 * 16);
    int s0 = st * 64, e0 = et * 64;
    int j = tid >> 2, part = tid & 3;

    const float4* p = (const float4*)(value + ((long)(b * S_ + s0 + j)) * E_ + e0 + part * 16);
    float4 x0 = p[0], x1 = p[1], x2 = p[2], x3 = p[3];
    *(f16x8*)&Ls[j][part * 16]     = cvt8(x0, x1);
    *(f16x8*)&Ls[j][part * 16 + 8] = cvt8(x2, x3);
    __syncthreads();

    int i = tid >> 2;  // local e row
    f16x8 o0, o1;
#pragma unroll
    for (int q = 0; q < 8; ++q) o0[q] = Ls[part * 16 + q][i];
#pragma unroll
    for (int q = 0; q < 8; ++q) o1[q] = Ls[part * 16 + 8 + q][i];
    _Float16* op = VT + ((long)(b * E_ + e0 + i)) * S_ + s0 + part * 16;
    *(f16x8*)op = o0;
    *((f16x8*)op + 1) = o1;
  } else {
    // ---- prep_rules: 96 blocks x 4 hr-groups (one wave each).
    int hr = (blk0 - 768) * 4 + (tid >> 6);
    int d = tid & 63;
    long idx = (long)hr * 64 + d;
    float w = RW[idx];
    float wi = 1.0f / w;
    float w2 = wi * wi;
    float rk = RK[idx];
    W1b[idx] = (__bf16)(-w2 * (LN2F / 524288.0f));
    W2b[idx] = (__bf16)(rk * w2 * (1.0f / 4096.0f));
    float part = rk * rk * w2;
    part += __shfl_xor(part, 1);
    part += __shfl_xor(part, 2);
    part += __shfl_xor(part, 4);
    part += __shfl_xor(part, 8);
    part += __shfl_xor(part, 16);
    part += __shfl_xor(part, 32);
    if (d == 0) cb[hr] = -part * (L2E / 128.0f);
  }
}

// ---------------------------------------------------------------------------
// Kernel 2b: MFMA value projection (reads VT), output TILED:
// VPTt[bh][c=r/32][dt=d/16][lo=d&15][gs=(r&31)/8][8]  (2048 f16/chunk, 33 chunks).
// ---------------------------------------------------------------------------
__global__ __launch_bounds__(256) void v_proj_mfma(const float* __restrict__ Wv,
                                                   const float* __restrict__ bv,
                                                   const _Float16* __restrict__ VT,
                                                   _Float16* __restrict__ VPTt) {
  __shared__ alignas(16) _Float16 As[2][64][72];
  __shared__ alignas(16) _Float16 Bs[2][64][72];

  int tid = threadIdx.x;
  int blk = blockIdx.x;
  int et = blk % 12;
  int rt = (blk / 12) % 17;
  int b  = blk / (12 * 17);
  int r0 = rt * 64, e0 = et * 64;
  int w = tid >> 6, l = tid & 63, lo = l & 15, g = l >> 4;
  int i = tid >> 2, part = tid & 3;

  bool rvalid = (r0 + i) < RS_;
  const float* wvp = Wv + (long)(r0 + i) * S_ + part * 16;
  const _Float16* vtp = VT + ((long)(b * E_ + e0 + i)) * S_ + part * 16;

  f32x4 acc[4];
#pragma unroll
  for (int ns = 0; ns < 4; ++ns)
#pragma unroll
    for (int q = 0; q < 4; ++q) acc[ns][q] = 0.f;

  auto STAGE = [&](int kb, int bufi) {
    float4 x0, x1, x2, x3;
    if (rvalid) {
      const float4* p = (const float4*)(wvp + kb);
      x0 = p[0]; x1 = p[1]; x2 = p[2]; x3 = p[3];
    } else {
      x0 = x1 = x2 = x3 = make_float4(0.f, 0.f, 0.f, 0.f);
    }
    *(f16x8*)&As[bufi][i][part * 16]     = cvt8(x0, x1);
    *(f16x8*)&As[bufi][i][part * 16 + 8] = cvt8(x2, x3);
    const uint4* vp4 = (const uint4*)(vtp + kb);
    uint4 b0 = vp4[0], b1 = vp4[1];
    *(uint4*)&Bs[bufi][i][part * 16]     = b0;
    *(uint4*)&Bs[bufi][i][part * 16 + 8] = b1;
  };

  STAGE(0, 0);
  __syncthreads();
  for (int k = 0; k < 16; ++k) {
    if (k < 15) STAGE((k + 1) * 64, (k + 1) & 1);
    int bi = k & 1;
#pragma unroll
    for (int kc = 0; kc < 2; ++kc) {
      f16x8 af = *(const f16x8*)&As[bi][w * 16 + lo][kc * 32 + g * 8];
#pragma unroll
      for (int ns = 0; ns < 4; ++ns) {
        f16x8 bf = *(const f16x8*)&Bs[bi][ns * 16 + lo][kc * 32 + g * 8];
        acc[ns] = mf16(af, bf, acc[ns]);
      }
    }
    __syncthreads();
  }

  float bvr[4];
#pragma unroll
  for (int reg = 0; reg < 4; ++reg) {
    int r = r0 + w * 16 + g * 4 + reg;
    bvr[reg] = (r < RS_) ? bv[r] : 0.f;
  }
  float* Ct = (float*)&As[0][0][0];  // Ct[d][rloc], stride 69
#pragma unroll
  for (int ns = 0; ns < 4; ++ns)
#pragma unroll
    for (int reg = 0; reg < 4; ++reg)
      Ct[(ns * 16 + lo) * 69 + w * 16 + g * 4 + reg] = acc[ns][reg] + bvr[reg];
  __syncthreads();

  if (r0 + part * 16 < RS_) {
    f16x8 o0, o1;
#pragma unroll
    for (int q = 0; q < 8; ++q) o0[q] = (_Float16)Ct[i * 69 + part * 16 + q];
#pragma unroll
    for (int q = 0; q < 8; ++q) o1[q] = (_Float16)Ct[i * 69 + part * 16 + 8 + q];
    int dtv = i >> 4, lov = i & 15;
    int c = rt * 2 + (part >> 1);
    _Float16* op = VPTt + (long)(b * H_ + et) * 67584 + (long)c * 2048 +
                   dtv * 512 + lov * 32 + ((part & 1) * 2) * 8;
    *(f16x8*)op = o0;
    *((f16x8*)op + 1) = o1;
  }
}

// ---------------------------------------------------------------------------
// Kernel 3: MFMA flash attention, 32-row q-tile, swapped QK^T, exp2 domain,
// speculative exp; K/V loads from TILED layouts (coalesced). grid = 768.
// ---------------------------------------------------------------------------
__global__ __launch_bounds__(256) void attn_mfma(
    const _Float16* __restrict__ Qh, const _Float16* __restrict__ KhT,
    const _Float16* __restrict__ VPTt, const __bf16* __restrict__ W1b,
    const __bf16* __restrict__ W2b, const float* __restrict__ cb,
    _Float16* __restrict__ AO) {
  __shared__ alignas(16) _Float16 Plds[4][16][40];   // [wave][q=lo][key]
  __shared__ alignas(16) _Float16 fwlds[2][16][40];  // [qsub][q=lo][rule]
  __shared__ float OBl[2][64][17];                   // half==1 O spill per qsub
  __shared__ float mrgM[2][16];
  __shared__ float mrgL[2][16];
  __shared__ float Olds[2][16][68];

  int tid = threadIdx.x;
  int wv = tid >> 6;            // wave id
  int qsub = wv >> 1;           // 0/1: q-subtile
  int half = wv & 1;            // 0/1: key half
  int l = tid & 63;
  int lo = l & 15, g = l >> 4;

  int bh = blockIdx.x >> 5;
  int qt = blockIdx.x & 31;
  int b = bh / H_, h = bh % H_;
  int s0 = qt * 32;

  const _Float16* Qw = Qh + ((long)bh * S_ + s0 + qsub * 16) * 64;
  const _Float16* Kt = KhT + (long)bh * 65536;
  const _Float16* Vt = VPTt + (long)bh * 67584;

  f16x8 qa0 = *(const f16x8*)(Qw + (long)lo * 64 + g * 8);
  f16x8 qa1 = *(const f16x8*)(Qw + (long)lo * 64 + 32 + g * 8);

  // ---- fuzzy branch (half==0 waves, one per qsub), exp2 domain
  if (half == 0) {
    bf16x8 qsq0, qsq1, qbf0, qbf1;
#pragma unroll
    for (int j = 0; j < 8; ++j) {
      float a0 = (float)qa0[j], a1 = (float)qa1[j];
      qbf0[j] = (__bf16)a0;
      qbf1[j] = (__bf16)a1;
      qsq0[j] = (__bf16)(a0 * a0);
      qsq1[j] = (__bf16)(a1 * a1);
    }
    f32x4 z[2];
#pragma unroll
    for (int t = 0; t < 2; ++t) {
#pragma unroll
      for (int j = 0; j < 4; ++j) z[t][j] = cb[h * R_ + t * 16 + g * 4 + j];
      const __bf16* w1p = W1b + ((long)h * R_ + t * 16 + lo) * 64;
      const __bf16* w2p = W2b + ((long)h * R_ + t * 16 + lo) * 64;
      bf16x8 b10 = *(const bf16x8*)(w1p + g * 8);
      bf16x8 b11 = *(const bf16x8*)(w1p + 32 + g * 8);
      bf16x8 b20 = *(const bf16x8*)(w2p + g * 8);
      bf16x8 b21 = *(const bf16x8*)(w2p + 32 + g * 8);
      z[t] = mbf(b10, qsq0, z[t]);
      z[t] = mbf(b11, qsq1, z[t]);
      z[t] = mbf(b20, qbf0, z[t]);
      z[t] = mbf(b21, qbf1, z[t]);
    }
    float zm = z[0][0];
#pragma unroll
    for (int j = 1; j < 4; ++j) zm = fmaxf(zm, z[0][j]);
#pragma unroll
    for (int j = 0; j < 4; ++j) zm = fmaxf(zm, z[1][j]);
    zm = fmaxf(zm, __shfl_xor(zm, 16));
    zm = fmaxf(zm, __shfl_xor(zm, 32));
    float ez[2][4], zsum = 0.f;
#pragma unroll
    for (int t = 0; t < 2; ++t)
#pragma unroll
      for (int j = 0; j < 4; ++j) { ez[t][j] = EXP2(z[t][j] - zm); zsum += ez[t][j]; }
    zsum += __shfl_xor(zsum, 16);
    zsum += __shfl_xor(zsum, 32);
    float zin = 1.0f / zsum;
#pragma unroll
    for (int t = 0; t < 2; ++t)
#pragma unroll
      for (int j = 0; j < 4; ++j)
        fwlds[qsub][lo][t * 16 + g * 4 + j] = (_Float16)(ez[t][j] * zin);
  }

  // ---- flash key loop: 16 chunks of 32 keys (this wave's key half)
  f32x4 O[4];
#pragma unroll
  for (int dt = 0; dt < 4; ++dt)
#pragma unroll
    for (int j = 0; j < 4; ++j) O[dt][j] = 0.f;
  float m = -__builtin_inff();
  float ellp = 0.f;

  int cg0 = half * 16;
  const _Float16* kc0 = Kt + (long)(cg0 * 8 + g) * 256 + lo * 8;
  const _Float16* kc1 = Kt + (long)(cg0 * 8 + g + 4) * 256 + lo * 8;
  f16x8 kf00 = *(const f16x8*)(kc0);
  f16x8 kf01 = *(const f16x8*)(kc1);
  f16x8 kf10 = *(const f16x8*)(kc0 + 128);
  f16x8 kf11 = *(const f16x8*)(kc1 + 128);

  for (int c = 0; c < 16; ++c) {
    int cg = cg0 + c;
    f16x8 nf00, nf01, nf10, nf11;
    if (c < 15) {  // prefetch next chunk's K fragments (coalesced tiles)
      const _Float16* np0 = Kt + (long)((cg + 1) * 8 + g) * 256 + lo * 8;
      const _Float16* np1 = Kt + (long)((cg + 1) * 8 + g + 4) * 256 + lo * 8;
      nf00 = *(const f16x8*)(np0);
      nf01 = *(const f16x8*)(np1);
      nf10 = *(const f16x8*)(np0 + 128);
      nf11 = *(const f16x8*)(np1 + 128);
    }
    f32x4 e0, e1;
#pragma unroll
    for (int j = 0; j < 4; ++j) { e0[j] = 0.f; e1[j] = 0.f; }
    e0 = mf16(kf00, qa0, e0);  // e0[j]: key cg*32+g*4+j, q=lo (exp2 domain)
    e0 = mf16(kf01, qa1, e0);
    e1 = mf16(kf10, qa0, e1);  // keys cg*32+16+g*4+j
    e1 = mf16(kf11, qa1, e1);

    // issue V loads early (coalesced 1KB per instruction)
    const _Float16* vchunk = Vt + (long)(cg + 1) * 2048 + lo * 32 + g * 8;
    f16x8 va0 = *(const f16x8*)(vchunk);
    f16x8 va1 = *(const f16x8*)(vchunk + 512);
    f16x8 va2 = *(const f16x8*)(vchunk + 1024);
    f16x8 va3 = *(const f16x8*)(vchunk + 1536);

    // speculative exps with stale m (overlaps the pmax reduce)
    float p0[4], p1[4];
#pragma unroll
    for (int j = 0; j < 4; ++j) {
      p0[j] = EXP2(e0[j] - m);
      p1[j] = EXP2(e1[j] - m);
    }
    float pmax = e0[0];
#pragma unroll
    for (int j = 1; j < 4; ++j) pmax = fmaxf(pmax, e0[j]);
#pragma unroll
    for (int j = 0; j < 4; ++j) pmax = fmaxf(pmax, e1[j]);
    pmax = fmaxf(pmax, __shfl_xor(pmax, 16));
    pmax = fmaxf(pmax, __shfl_xor(pmax, 32));
    if (__any(pmax > m + 11.5f)) {  // rescale needed (rare): redo
      float mn = fmaxf(m, pmax);
      float sc = EXP2(m - mn);
      ellp *= sc;
#pragma unroll
      for (int dt = 0; dt < 4; ++dt)
#pragma unroll
        for (int j = 0; j < 4; ++j) O[dt][j] *= sc;
#pragma unroll
      for (int j = 0; j < 4; ++j) {
        p0[j] = EXP2(e0[j] - mn);
        p1[j] = EXP2(e1[j] - mn);
      }
      m = mn;
    }
    float s8 = 0.f;
#pragma unroll
    for (int j = 0; j < 4; ++j) s8 += p0[j] + p1[j];
    ellp += s8;
    // packed P write: 4 x b32
    fp16x2 w0 = __builtin_amdgcn_cvt_pkrtz(p0[0], p0[1]);
    fp16x2 w1 = __builtin_amdgcn_cvt_pkrtz(p0[2], p0[3]);
    fp16x2 w2 = __builtin_amdgcn_cvt_pkrtz(p1[0], p1[1]);
    fp16x2 w3 = __builtin_amdgcn_cvt_pkrtz(p1[2], p1[3]);
    *(fp16x2*)&Plds[wv][lo][g * 4]          = w0;
    *(fp16x2*)&Plds[wv][lo][g * 4 + 2]      = w1;
    *(fp16x2*)&Plds[wv][lo][16 + g * 4]     = w2;
    *(fp16x2*)&Plds[wv][lo][16 + g * 4 + 2] = w3;
    f16x8 pb = *(const f16x8*)&Plds[wv][lo][g * 8];  // B-frag: row q=lo
    O[0] = mf16(va0, pb, O[0]);
    O[1] = mf16(va1, pb, O[1]);
    O[2] = mf16(va2, pb, O[2]);
    O[3] = mf16(va3, pb, O[3]);
    kf00 = nf00; kf01 = nf01; kf10 = nf10; kf11 = nf11;
  }

  // per-wave ell: cross-g reduce
  float ell = ellp;
  ell += __shfl_xor(ell, 16);
  ell += __shfl_xor(ell, 32);

  // ---- merge the pair's two states (per-lane, q = lo)
  if (half == 1) {
#pragma unroll
    for (int dt = 0; dt < 4; ++dt)
#pragma unroll
      for (int j = 0; j < 4; ++j) OBl[qsub][dt * 16 + g * 4 + j][lo] = O[dt][j];
    if (l < 16) {
      mrgM[qsub][l] = m;
      mrgL[qsub][l] = ell;
    }
  }
  __syncthreads();
  if (half == 0) {
    float mB = mrgM[qsub][lo];
    float lB = mrgL[qsub][lo];
    float m12 = fmaxf(m, mB);
    float sA = EXP2(m - m12);
    float sB = EXP2(mB - m12);
    float iv = 1.0f / (ell * sA + lB * sB);
    float fA = sA * iv, fB = sB * iv;
#pragma unroll
    for (int dt = 0; dt < 4; ++dt)
#pragma unroll
      for (int j = 0; j < 4; ++j)
        O[dt][j] = O[dt][j] * fA + OBl[qsub][dt * 16 + g * 4 + j][lo] * fB;
    // rules contribution (chunk 0 of tiled V, already normalized)
    f16x8 fb = *(const f16x8*)&fwlds[qsub][lo][g * 8];
    const _Float16* vrules = Vt + lo * 32 + g * 8;
#pragma unroll
    for (int dt = 0; dt < 4; ++dt) {
      f16x8 va = *(const f16x8*)(vrules + dt * 512);
      O[dt] = mf16(va, fb, O[dt]);
    }
#pragma unroll
    for (int dt = 0; dt < 4; ++dt)
#pragma unroll
      for (int j = 0; j < 4; ++j) Olds[qsub][lo][dt * 16 + g * 4 + j] = O[dt][j];
  }
  __syncthreads();
  for (int idx = tid; idx < 2 * 16 * 64; idx += 256) {
    int pp = idx >> 10;
    int row = (idx >> 6) & 15;
    int col = idx & 63;
    AO[((long)(b * S_ + s0 + pp * 16 + row)) * E_ + h * 64 + col] =
        (_Float16)Olds[pp][row][col];
  }
}

// ---------------------------------------------------------------------------
// Kernel 4: MFMA output projection. C[n,e] = sum_f AO16[n,f]*Wo[e,f] + bo[e].
// ---------------------------------------------------------------------------
__global__ __launch_bounds__(256) void out_proj_mfma(const _Float16* __restrict__ AO16,
                                                     const float* __restrict__ Wo,
                                                     const float* __restrict__ bo,
                                                     float* __restrict__ Out) {
  __shared__ alignas(16) _Float16 As[2][64][72];
  __shared__ alignas(16) _Float16 Bs[2][64][72];

  int tid = threadIdx.x;
  int blk = blockIdx.x;
  int et = blk % 12;
  int nt = blk / 12;
  int n0 = nt * 64, e0 = et * 64;
  int w = tid >> 6, l = tid & 63, lo = l & 15, g = l >> 4;
  int i = tid >> 2, part = tid & 3;

  const _Float16* aop = AO16 + (long)(n0 + i) * E_ + part * 16;
  const float* wop = Wo + (long)(e0 + i) * E_ + part * 16;

  f32x4 acc[4];
#pragma unroll
  for (int ns = 0; ns < 4; ++ns)
#pragma unroll
    for (int q = 0; q < 4; ++q) acc[ns][q] = 0.f;

  auto STAGE = [&](int kb, int bufi) {
    const uint4* ap4 = (const uint4*)(aop + kb);
    uint4 a0 = ap4[0], a1 = ap4[1];
    *(uint4*)&As[bufi][i][part * 16]     = a0;
    *(uint4*)&As[bufi][i][part * 16 + 8] = a1;
    const float4* p = (const float4*)(wop + kb);
    float4 x0 = p[0], x1 = p[1], x2 = p[2], x3 = p[3];
    *(f16x8*)&Bs[bufi][i][part * 16]     = cvt8(x0, x1);
    *(f16x8*)&Bs[bufi][i][part * 16 + 8] = cvt8(x2, x3);
  };

  STAGE(0, 0);
  __syncthreads();
  for (int k = 0; k < 12; ++k) {
    if (k < 11) STAGE((k + 1) * 64, (k + 1) & 1);
    int bi = k & 1;
#pragma unroll
    for (int kc = 0; kc < 2; ++kc) {
      f16x8 af = *(const f16x8*)&As[bi][w * 16 + lo][kc * 32 + g * 8];
#pragma unroll
      for (int ns = 0; ns < 4; ++ns) {
        f16x8 bf = *(const f16x8*)&Bs[bi][ns * 16 + lo][kc * 32 + g * 8];
        acc[ns] = mf16(af, bf, acc[ns]);
      }
    }
    __syncthreads();
  }

  float* Cs = (float*)&As[0][0][0];  // Cs[n][e], stride 69
#pragma unroll
  for (int ns = 0; ns < 4; ++ns)
#pragma unroll
    for (int reg = 0; reg < 4; ++reg)
      Cs[(w * 16 + g * 4 + reg) * 69 + ns * 16 + lo] = acc[ns][reg];
  __syncthreads();

  float tmp[16];
#pragma unroll
  for (int q = 0; q < 16; ++q)
    tmp[q] = Cs[i * 69 + part * 16 + q] + bo[e0 + part * 16 + q];
  float* outp = Out + (long)(n0 + i) * E_ + e0 + part * 16;
#pragma unroll
  for (int q4 = 0; q4 < 4; ++q4)
    ((float4*)outp)[q4] = make_float4(tmp[q4 * 4], tmp[q4 * 4 + 1], tmp[q4 * 4 + 2], tmp[q4 * 4 + 3]);
}

extern "C" void kernel_launch(void* const* d_in, const int* in_sizes, int n_in,
                              void* d_out, int out_size, void* d_ws, size_t ws_size,
                              hipStream_t stream) {
  const float* query = (const float*)d_in[0];
  const float* key   = (const float*)d_in[1];
  const float* value = (const float*)d_in[2];
  const float* rk    = (const float*)d_in[3];
  const float* rw    = (const float*)d_in[4];
  const float* Wq    = (const float*)d_in[5];
  const float* Wk    = (const float*)d_in[6];
  const float* Wv    = (const float*)d_in[7];
  const float* bv    = (const float*)d_in[8];
  const float* Wo    = (const float*)d_in[9];
  const float* bo    = (const float*)d_in[10];
  float* out = (float*)d_out;

  char* wsb = (char*)d_ws;
  _Float16* Qh   = (_Float16*)(wsb);                 // 3,145,728 B
  _Float16* KhT  = (_Float16*)(wsb + 3145728);       // 3,145,728 B (tiled)
  _Float16* VPTt = (_Float16*)(wsb + 6291456);       // 3,244,032 B (tiled)
  _Float16* VT   = (_Float16*)(wsb + 9535488);       // 3,145,728 B (aliased w/ AO16)
  _Float16* AO16 = VT;  // VT dead after v_proj_mfma; attn writes AO16 after
  __bf16* W1b = (__bf16*)(wsb + 12681216);           // 49,152 B
  __bf16* W2b = (__bf16*)(wsb + 12730368);           // 49,152 B
  float* cb   = (float*)(wsb + 12779520);            // 1,536 B

  frontend<<<864, 256, 0, stream>>>(query, key, Wq, Wk, value, rk, rw,
                                    Qh, KhT, VT, W1b, W2b, cb);
  v_proj_mfma<<<2 * 17 * 12, 256, 0, stream>>>(Wv, bv, VT, VPTt);
  attn_mfma<<<768, 256, 0, stream>>>(Qh, KhT, VPTt, W1b, W2b, cb, AO16);
  out_proj_mfma<<<32 * 12, 256, 0, stream>>>(AO16, Wo, bo, out);
}